// Round 11
// baseline (1247.335 us; speedup 1.0000x reference)
//
#include <hip/hip_runtime.h>
#include <math.h>

// B=1024, D=128, DH=64, H=512 ; rows = B*D = 131072
// Hc (f16): [1024, 8192], Hc[b, k*128+d] = h[b,d,k]

typedef __attribute__((ext_vector_type(8))) short bf16x8;      // raw 16B mover / bf16
typedef __attribute__((ext_vector_type(8))) _Float16 f16x8;
typedef __attribute__((ext_vector_type(4))) float f32x4;

static __device__ __forceinline__ unsigned short f2bf(float f) {
    unsigned u = __builtin_bit_cast(unsigned, f);
    unsigned r = (u + 0x7FFFu + ((u >> 16) & 1u)) >> 16;
    return (unsigned short)r;
}
static __device__ __forceinline__ unsigned pk_f16(float a, float b) {
    auto h = __builtin_amdgcn_cvt_pkrtz(a, b);   // __fp16 ext_vector_type(2)
    return __builtin_bit_cast(unsigned, h);
}

static __device__ __forceinline__ float fexp2(float x) {
#if __has_builtin(__builtin_amdgcn_exp2f)
    return __builtin_amdgcn_exp2f(x);
#else
    float r; asm("v_exp_f32 %0, %1" : "=v"(r) : "v"(x)); return r;
#endif
}
static __device__ __forceinline__ float frcp(float x) {
#if __has_builtin(__builtin_amdgcn_rcpf)
    return __builtin_amdgcn_rcpf(x);
#else
    float r; asm("v_rcp_f32 %0, %1" : "=v"(r) : "v"(x)); return r;
#endif
}
// tanh(x) = 1 - 2/(1+e^{2x}); exp2-based, ~1e-6 abs err, saturates correctly.
static __device__ __forceinline__ float fast_tanh(float x) {
    const float e = fexp2(x * 2.8853900817779268f);   // e^{2x}
    const float r = frcp(1.f + e);
    return __builtin_fmaf(-2.f, r, 1.f);
}

// ---------------------------------------------------------------------------
// Merged prep: blocks [0,256) W1f/W1s ; [256,384) W0t ; [384,896) W1t ;
//              [896,898) S1.
// W1f[j][k] = f16(W1d[k][j]) ; W1s[j][k] = f16(W0d[512+k] * W1d[k][j])
// W0t[n][k] = f16(W0d[2+k][n]) ; S1[j] = sum_k W0d[512+k]*W1d[k][j]
// W1t[n][k] (bf16, MADE-masked).
// ---------------------------------------------------------------------------
__global__ __launch_bounds__(256, 4)
void prep_k(const float* __restrict__ W1d, const float* __restrict__ W0d,
            const float* __restrict__ W1a, const float* __restrict__ W1b,
            _Float16* __restrict__ W1f, _Float16* __restrict__ W1s,
            _Float16* __restrict__ W0t, float* __restrict__ S1,
            unsigned short* __restrict__ W1t)
{
    __shared__ float tile[32][33];
    const int bidx = blockIdx.x;
    const int tid  = threadIdx.x;

    if (bidx < 256) {
        const int n0 = (bidx & 15) * 32, k0 = (bidx >> 4) * 32;
        const int c = tid & 31, r4 = tid >> 5;
        #pragma unroll
        for (int i = 0; i < 4; ++i) {
            const int r = r4 * 4 + i;
            tile[r][c] = W1d[(k0 + r) * 512 + n0 + c];
        }
        __syncthreads();
        #pragma unroll
        for (int i = 0; i < 4; ++i) {
            const int r = r4 * 4 + i;                 // output row (j)
            const float v   = tile[c][r];             // = W1d[k0+c][n0+r]
            const float w01 = W0d[512 + k0 + c];
            W1f[(n0 + r) * 512 + k0 + c] = (_Float16)v;
            W1s[(n0 + r) * 512 + k0 + c] = (_Float16)(w01 * v);
        }
    } else if (bidx < 384) {
        const int idx = (bidx - 256) * 256 + tid;     // 0..32767
        const int n = idx & 511, k = idx >> 9;
        W0t[n * 64 + k] = (_Float16)W0d[(2 + k) * 512 + n];
    } else if (bidx < 896) {
        const int rel = bidx - 384;                   // 0..511
        const int n0 = (rel & 31) * 32;               // 0..1023
        const int k0 = (rel >> 5) * 32;               // 0..511
        const float* __restrict__ src = (n0 < 512) ? W1a : W1b;
        const int nrel0 = n0 & 511;
        const int c = tid & 31, r4 = tid >> 5;
        #pragma unroll
        for (int i = 0; i < 4; ++i) {
            const int r = r4 * 4 + i;
            tile[r][c] = src[(k0 + r) * 512 + nrel0 + c];
        }
        __syncthreads();
        #pragma unroll
        for (int i = 0; i < 4; ++i) {
            const int r = r4 * 4 + i;
            const int n = n0 + r;
            const int k = k0 + c;
            const bool keep = (k % 127) <= ((n & 511) % 127);
            W1t[(size_t)n * 512 + k] = keep ? f2bf(tile[c][r]) : (unsigned short)0;
        }
    } else {
        const int j = (bidx - 896) * 256 + tid;       // 0..511
        float s = 0.f;
        #pragma unroll 8
        for (int k = 0; k < 512; ++k)
            s += W0d[512 + k] * W1d[k * 512 + j];
        S1[j] = s;
    }
}

// ---------------------------------------------------------------------------
// MADE layer 1, both nets: x[1024,128] @ (W0 .* mask1) -> h1cat bf16 [1024][1024]
// ---------------------------------------------------------------------------
__global__ __launch_bounds__(256, 4)
void made1_k(const float* __restrict__ x,
             const float* __restrict__ Wn1, const float* __restrict__ Wn2,
             const float* __restrict__ bn1, const float* __restrict__ bn2,
             unsigned short* __restrict__ h1cat)
{
    __shared__ float As[16][68];
    __shared__ float Bs[16][68];

    const int tid = threadIdx.x;
    const int bn  = blockIdx.x;          // 0..15 : net = bn>>3
    const int bm  = blockIdx.y;          // 0..15
    const int net = bn >> 3;
    const int nb  = (bn & 7) * 64;
    const int tx = tid & 15, ty = tid >> 4;
    const int m_base = bm * 64;

    const float* __restrict__ W  = net ? Wn2 : Wn1;
    const float* __restrict__ bi = net ? bn2 : bn1;

    float acc[4][4] = {};

    for (int k0 = 0; k0 < 128; k0 += 16) {
        {
            const int m  = tid >> 2;
            const int kk = (tid & 3) * 4;
            const float4 a4 = *reinterpret_cast<const float4*>(&x[(size_t)(m_base + m) * 128 + k0 + kk]);
            As[kk + 0][m] = a4.x; As[kk + 1][m] = a4.y;
            As[kk + 2][m] = a4.z; As[kk + 3][m] = a4.w;
        }
        {
            const int kk = tid >> 4;
            const int nn = (tid & 15) * 4;
            const int gk = k0 + kk;
            const int gn = nb + nn;
            float4 b4 = *reinterpret_cast<const float4*>(&W[gk * 512 + gn]);
            float bv[4] = {b4.x, b4.y, b4.z, b4.w};
            #pragma unroll
            for (int j = 0; j < 4; ++j) {
                const int n = gn + j;
                const bool keep = net ? ((127 - gk) <= (n % 127)) : (gk <= (n % 127));
                Bs[kk][nn + j] = keep ? bv[j] : 0.f;
            }
        }
        __syncthreads();
        #pragma unroll
        for (int kk = 0; kk < 16; ++kk) {
            const float4 a4 = *reinterpret_cast<const float4*>(&As[kk][ty * 4]);
            const float4 b4 = *reinterpret_cast<const float4*>(&Bs[kk][tx * 4]);
            const float av[4] = {a4.x, a4.y, a4.z, a4.w};
            const float bv[4] = {b4.x, b4.y, b4.z, b4.w};
            #pragma unroll
            for (int i = 0; i < 4; ++i)
                #pragma unroll
                for (int j = 0; j < 4; ++j)
                    acc[i][j] += av[i] * bv[j];
        }
        __syncthreads();
    }

    #pragma unroll
    for (int i = 0; i < 4; ++i) {
        const int m = m_base + ty * 4 + i;
        #pragma unroll
        for (int j = 0; j < 4; ++j) {
            const int n = nb + tx * 4 + j;
            const float v = fmaxf(acc[i][j] + bi[n], 0.f);
            h1cat[(size_t)m * 1024 + net * 512 + n] = f2bf(v);
        }
    }
}

// ---------------------------------------------------------------------------
// MADE W2 masked+transposed: W2t[n 0..8191][k 0..1023] bf16
// ---------------------------------------------------------------------------
__global__ __launch_bounds__(256, 4)
void prep_w2t_k(const float* __restrict__ W2a, const float* __restrict__ W2b,
                unsigned short* __restrict__ W2t)
{
    __shared__ float tile[32][33];
    const int tid = threadIdx.x;
    const int n0 = blockIdx.x * 32;      // 0..8191
    const int k0 = blockIdx.y * 32;      // 0..1023
    const float* __restrict__ src = (k0 < 512) ? W2a : W2b;
    const int krel0 = k0 & 511;
    const bool net1 = (k0 >= 512);
    const int c = tid & 31, r4 = tid >> 5;
    #pragma unroll
    for (int i = 0; i < 4; ++i) {
        const int r = r4 * 4 + i;        // k-offset
        tile[r][c] = src[(size_t)(krel0 + r) * 8192 + n0 + c];
    }
    __syncthreads();
    #pragma unroll
    for (int i = 0; i < 4; ++i) {
        const int r = r4 * 4 + i;        // n-offset
        const int n = n0 + r;
        const int k = k0 + c;
        const int km = (k & 511) % 127;
        const int dg = n & 127;
        const bool keep = net1 ? (km < 127 - dg) : (km < dg);
        W2t[(size_t)n * 1024 + k] = keep ? f2bf(tile[c][r]) : (unsigned short)0;
    }
}

// ---------------------------------------------------------------------------
// MADE layer 2: h2 = relu(h1 @ W1m + b). Barrier-free MFMA, tile 64x64.
// ---------------------------------------------------------------------------
__global__ __launch_bounds__(512, 2)
void gemm2_k(const unsigned short* __restrict__ h1cat,
             const unsigned short* __restrict__ W1t,
             const float* __restrict__ ba, const float* __restrict__ bb,
             unsigned short* __restrict__ h2cat)
{
    const int tid = threadIdx.x;
    const int n0 = blockIdx.x * 64;
    const int m0 = blockIdx.y * 64;
    const int lane = tid & 63, w = tid >> 6;
    const int l15 = lane & 15, l16 = lane >> 4;
    const int wm = w & 3, wn = w >> 2;
    const int net = n0 >> 9;
    const float* __restrict__ bi = net ? bb : ba;

    const unsigned short* Ab = h1cat + (size_t)(m0 + wm * 16 + l15) * 1024 + net * 512 + l16 * 8;
    const unsigned short* Bb = W1t + (size_t)(n0 + wn * 32 + l15) * 512 + l16 * 8;

    f32x4 acc[2] = {};
    bf16x8 a0, b0[2], a1, b1[2];
    a0 = *(const bf16x8*)(Ab);
    b0[0] = *(const bf16x8*)(Bb);
    b0[1] = *(const bf16x8*)(Bb + 16 * 512);

    #pragma unroll
    for (int s = 0; s < 15; ++s) {
        const int off = (s + 1) * 32;
        a1 = *(const bf16x8*)(Ab + off);
        b1[0] = *(const bf16x8*)(Bb + off);
        b1[1] = *(const bf16x8*)(Bb + 16 * 512 + off);
        acc[0] = __builtin_amdgcn_mfma_f32_16x16x32_bf16(a0, b0[0], acc[0], 0, 0, 0);
        acc[1] = __builtin_amdgcn_mfma_f32_16x16x32_bf16(a0, b0[1], acc[1], 0, 0, 0);
        a0 = a1; b0[0] = b1[0]; b0[1] = b1[1];
    }
    acc[0] = __builtin_amdgcn_mfma_f32_16x16x32_bf16(a0, b0[0], acc[0], 0, 0, 0);
    acc[1] = __builtin_amdgcn_mfma_f32_16x16x32_bf16(a0, b0[1], acc[1], 0, 0, 0);

    #pragma unroll
    for (int nt = 0; nt < 2; ++nt) {
        const int n = n0 + wn * 32 + nt * 16 + l15;
        const float bv = bi[n & 511];
        #pragma unroll
        for (int e = 0; e < 4; ++e) {
            const float v = fmaxf(acc[nt][e] + bv, 0.f);
            h2cat[(size_t)(m0 + wm * 16 + l16 * 4 + e) * 1024 + n] = f2bf(v);
        }
    }
}

// ---------------------------------------------------------------------------
// MADE layer 3, both nets fused over K=1024: Hc(f16) = h2cat @ W2t^T + bias
// ---------------------------------------------------------------------------
__global__ __launch_bounds__(512, 2)
void gemm3_k(const unsigned short* __restrict__ h2cat,
             const unsigned short* __restrict__ W2t,
             const float* __restrict__ ba, const float* __restrict__ bb,
             _Float16* __restrict__ Hc)
{
    const int tid = threadIdx.x;
    const int n0 = blockIdx.x * 128, m0 = blockIdx.y * 128;
    const int lane = tid & 63, w = tid >> 6;
    const int l15 = lane & 15, l16 = lane >> 4;
    const int wm = w & 3, wn = w >> 2;

    const unsigned short* Ab = h2cat + (size_t)(m0 + wm * 32 + l15) * 1024 + l16 * 8;
    const unsigned short* Bb = W2t + (size_t)(n0 + wn * 64 + l15) * 1024 + l16 * 8;

    f32x4 acc[2][4] = {};
    bf16x8 a0[2], b0[4], a1[2], b1[4];
    #pragma unroll
    for (int mt = 0; mt < 2; ++mt) a0[mt] = *(const bf16x8*)(Ab + mt * 16 * 1024);
    #pragma unroll
    for (int nt = 0; nt < 4; ++nt) b0[nt] = *(const bf16x8*)(Bb + nt * 16 * 1024);

    for (int s = 0; s < 32; ++s) {
        if (s < 31) {
            const int off = (s + 1) * 32;
            #pragma unroll
            for (int mt = 0; mt < 2; ++mt) a1[mt] = *(const bf16x8*)(Ab + mt * 16 * 1024 + off);
            #pragma unroll
            for (int nt = 0; nt < 4; ++nt) b1[nt] = *(const bf16x8*)(Bb + nt * 16 * 1024 + off);
        }
        #pragma unroll
        for (int mt = 0; mt < 2; ++mt)
            #pragma unroll
            for (int nt = 0; nt < 4; ++nt)
                acc[mt][nt] = __builtin_amdgcn_mfma_f32_16x16x32_bf16(a0[mt], b0[nt], acc[mt][nt], 0, 0, 0);
        #pragma unroll
        for (int mt = 0; mt < 2; ++mt) a0[mt] = a1[mt];
        #pragma unroll
        for (int nt = 0; nt < 4; ++nt) b0[nt] = b1[nt];
    }

    #pragma unroll
    for (int nt = 0; nt < 4; ++nt) {
        const int n = n0 + wn * 64 + nt * 16 + l15;
        const float bsum = ba[n] + bb[n];
        #pragma unroll
        for (int mt = 0; mt < 2; ++mt) {
            const int mrow = m0 + wm * 32 + mt * 16 + l16 * 4;
            #pragma unroll
            for (int e = 0; e < 4; ++e)
                Hc[(size_t)(mrow + e) * 8192 + n] = (_Float16)(acc[mt][nt][e] + bsum);
        }
    }
}

// ---------------------------------------------------------------------------
// Fused dimwise MLP + exact JVP. r11: occupancy push — f16 z^2-trick (no tA,
// LDS 39KB) + lean phase-2 (4 groups x 16 cols, acc=16, ~81 regs) +
// __launch_bounds__(512,6) -> target 3 blocks/CU (24 waves).
// LDS: zA [0,34816) Hstage [34816,38912) xbuf [38912,39040)
// zA layout: byte(k, brow) = (k>>3)*272 + (brow&15)*16 + (k&7)*2
//            (+17408 for brow>=16)
// ---------------------------------------------------------------------------
__global__ __launch_bounds__(512, 6)
void dimwise_k(const _Float16* __restrict__ Hc,
               const float* __restrict__ x, const float* __restrict__ t,
               const _Float16* __restrict__ W1f, const _Float16* __restrict__ W1s,
               const _Float16* __restrict__ W0t, const float* __restrict__ S1,
               const float* __restrict__ W0, const float* __restrict__ b0,
               const float* __restrict__ b1,
               const float* __restrict__ W2, const float* __restrict__ b2,
               float* __restrict__ out)
{
    __shared__ __align__(16) char smem[39040];

    const int tid  = threadIdx.x;
    // bijective XCD swizzle: 4 d-blocks of one batch row share an XCD L2.
    const int bid  = (blockIdx.x & 7) * 512 + (blockIdx.x >> 3);
    const int row0 = bid * 32;
    const int b    = row0 >> 7;
    const int d0   = row0 & 127;

    const int lane = tid & 63;
    const int w    = tid >> 6;          // wave 0..7, owns n in [w*64, w*64+64)
    const int l15 = lane & 15, l16 = lane >> 4;

    // ---- phase 0: stage Hc tile [32 row][64 k] (XOR-swizzled) + x ----
    if (tid < 256) {
        const int k    = tid >> 2;            // 0..63
        const int part = tid & 3;             // d offset part*8
        const bf16x8 hv = *(const bf16x8*)((const unsigned short*)Hc
                                           + (size_t)b * 8192 + k * 128 + d0 + part * 8);
        #pragma unroll
        for (int j = 0; j < 8; ++j) {
            const int row = part * 8 + j;
            const int byte = 34816 + row * 128 + ((2 * k) ^ ((row & 7) << 4));
            *(unsigned short*)(smem + byte) = (unsigned short)hv[j];
        }
    }
    if (tid < 32) ((float*)(smem + 38912))[tid] = x[b * 128 + d0 + tid];
    __syncthreads();

    // ---- phase 1: z1pre via SWAPPED MFMA (A=W0t rows=n, B=H cols=brow) ----
    // output: col=l15 -> brow (within mt-tile), row=l16*4+e -> n (within nt)
    f32x4 zacc[2][4] = {};   // [mt][nt]
    #pragma unroll
    for (int ks = 0; ks < 2; ++ks) {
        f16x8 af[2];
        #pragma unroll
        for (int mt = 0; mt < 2; ++mt) {
            const int row = mt * 16 + l15;
            const int inner = (ks * 64 + l16 * 16) ^ ((l15 & 7) << 4);
            af[mt] = *(const f16x8*)(smem + 34816 + row * 128 + inner);
        }
        #pragma unroll
        for (int nt = 0; nt < 4; ++nt) {
            const int n = w * 64 + nt * 16 + l15;
            const f16x8 wf = *(const f16x8*)(W0t + n * 64 + ks * 32 + l16 * 8);
            #pragma unroll
            for (int mt = 0; mt < 2; ++mt)
                zacc[mt][nt] = __builtin_amdgcn_mfma_f32_16x16x32_f16(wf, af[mt], zacc[mt][nt], 0, 0, 0);
        }
    }
    {
        const float tv = t[0];
        const float* xb = (const float*)(smem + 38912);
        float xv[2];
        #pragma unroll
        for (int mt = 0; mt < 2; ++mt) xv[mt] = xb[mt * 16 + l15];
        #pragma unroll
        for (int nt = 0; nt < 4; ++nt) {
            const int nq = w * 64 + nt * 16 + l16 * 4;     // 4 consecutive n
            const float4 b04 = *(const float4*)&b0[nq];
            const float4 wr0 = *(const float4*)&W0[nq];
            const float4 wr1 = *(const float4*)&W0[512 + nq];
            const int kboff = (nq >> 3) * 272 + (nq & 7) * 2;
            #pragma unroll
            for (int mt = 0; mt < 2; ++mt) {
                float zq[4];
                #pragma unroll
                for (int e = 0; e < 4; ++e) {
                    const float be  = (e == 0) ? b04.x : (e == 1) ? b04.y : (e == 2) ? b04.z : b04.w;
                    const float w0e = (e == 0) ? wr0.x : (e == 1) ? wr0.y : (e == 2) ? wr0.z : wr0.w;
                    const float w1e = (e == 0) ? wr1.x : (e == 1) ? wr1.y : (e == 2) ? wr1.z : wr1.w;
                    const float pre = zacc[mt][nt][e] + be + tv * w0e + xv[mt] * w1e;
                    zq[e] = fast_tanh(pre);
                }
                const int off = mt * 17408 + kboff + l15 * 16;
                *(uint2*)(smem + off) = make_uint2(pk_f16(zq[0], zq[1]), pk_f16(zq[2], zq[3]));
            }
        }
    }
    __syncthreads();

    // ---- phase 2+3 fused: 4 groups x 16 cols; z-path (W1f) + z^2-path (W1s)
    const int aoff0 = l15 * 16 + l16 * 272;     // + ks*1088

    float py[2][4] = {}, pj[2][4] = {};

    #pragma unroll
    for (int g = 0; g < 4; ++g) {
        const int n = w * 64 + g * 16 + l15;
        const float b1v = b1[n];
        const float w2v = W2[n];
        const float s1v = S1[n];
        const _Float16* __restrict__ Wfb = W1f + (size_t)n * 512 + l16 * 8;
        const _Float16* __restrict__ Wsb = W1s + (size_t)n * 512 + l16 * 8;

        f32x4 accp[2] = {}, acct[2] = {};       // [mt]
        f16x8 za0[2], za1[2], bw0, bw1, bs0, bs1;

        #pragma unroll
        for (int mt = 0; mt < 2; ++mt)
            za0[mt] = *(const f16x8*)(smem + mt * 17408 + aoff0);
        bw0 = *(const f16x8*)(Wfb);
        bs0 = *(const f16x8*)(Wsb);

        #pragma unroll
        for (int ks = 0; ks < 16; ++ks) {
            if (ks < 15) {
                const int ao = aoff0 + (ks + 1) * 1088;
                #pragma unroll
                for (int mt = 0; mt < 2; ++mt)
                    za1[mt] = *(const f16x8*)(smem + mt * 17408 + ao);
                bw1 = *(const f16x8*)(Wfb + (ks + 1) * 32);
                bs1 = *(const f16x8*)(Wsb + (ks + 1) * 32);
            }
            #pragma unroll
            for (int mt = 0; mt < 2; ++mt) {
                accp[mt] = __builtin_amdgcn_mfma_f32_16x16x32_f16(za0[mt], bw0, accp[mt], 0, 0, 0);
                const f16x8 zsq = za0[mt] * za0[mt];
                acct[mt] = __builtin_amdgcn_mfma_f32_16x16x32_f16(zsq, bs0, acct[mt], 0, 0, 0);
            }
            #pragma unroll
            for (int mt = 0; mt < 2; ++mt) za0[mt] = za1[mt];
            bw0 = bw1; bs0 = bs1;
        }

        // group epilogue: tanh/JVP + partial 512->1 dot
        #pragma unroll
        for (int mt = 0; mt < 2; ++mt)
            #pragma unroll
            for (int e = 0; e < 4; ++e) {
                const float z2  = fast_tanh(accp[mt][e] + b1v);
                const float tp  = s1v - acct[mt][e];          // tpre2
                const float dz2 = (1.f - z2 * z2) * tp;
                py[mt][e] += z2  * w2v;
                pj[mt][e] += dz2 * w2v;
            }
    }

    // ---- cross-lane + cross-wave reduction ----
    #pragma unroll
    for (int off = 1; off < 16; off <<= 1)
        #pragma unroll
        for (int mt = 0; mt < 2; ++mt)
            #pragma unroll
            for (int e = 0; e < 4; ++e) {
                py[mt][e] += __shfl_xor(py[mt][e], off);
                pj[mt][e] += __shfl_xor(pj[mt][e], off);
            }

    __syncthreads();
    float* part = (float*)smem;         // [8 w][2 mt][16 row][2]
    if (l15 == 0) {
        const int q = l16;
        #pragma unroll
        for (int mt = 0; mt < 2; ++mt)
            #pragma unroll
            for (int e = 0; e < 4; ++e) {
                const int idx = ((w * 2 + mt) * 16 + 4 * q + e) * 2;
                part[idx]     = py[mt][e];
                part[idx + 1] = pj[mt][e];
            }
    }
    __syncthreads();
    if (tid < 64) {
        const int mt = tid >> 5, row = (tid >> 1) & 15, wh = tid & 1;
        float s = 0.f;
        #pragma unroll
        for (int w8 = 0; w8 < 8; ++w8)
            s += part[((w8 * 2 + mt) * 16 + row) * 2 + wh];
        const int grow = row0 + mt * 16 + row;
        if (wh == 0) out[grow] = s + b2[0];
        else         out[131072 + grow] = s;
    }
}

// ---------------------------------------------------------------------------
extern "C" void kernel_launch(void* const* d_in, const int* in_sizes, int n_in,
                              void* d_out, int out_size, void* d_ws, size_t ws_size,
                              hipStream_t stream)
{
    (void)in_sizes; (void)n_in; (void)out_size; (void)ws_size;

    const float* t     = (const float*)d_in[0];
    const float* x     = (const float*)d_in[1];
    const float* m1_W0 = (const float*)d_in[2];
    const float* m1_b0 = (const float*)d_in[3];
    const float* m1_W1 = (const float*)d_in[4];
    const float* m1_b1 = (const float*)d_in[5];
    const float* m1_W2 = (const float*)d_in[6];
    const float* m1_b2 = (const float*)d_in[7];
    const float* m2_W0 = (const float*)d_in[8];
    const float* m2_b0 = (const float*)d_in[9];
    const float* m2_W1 = (const float*)d_in[10];
    const float* m2_b1 = (const float*)d_in[11];
    const float* m2_W2 = (const float*)d_in[12];
    const float* m2_b2 = (const float*)d_in[13];
    const float* d_W0  = (const float*)d_in[14];
    const float* d_b0  = (const float*)d_in[15];
    const float* d_W1  = (const float*)d_in[16];
    const float* d_b1  = (const float*)d_in[17];
    const float* d_W2  = (const float*)d_in[18];
    const float* d_b2  = (const float*)d_in[19];

    // ws layout (peak 0x2320000 = 36.8MB):
    // [0x0000000] W1f 512K ; [0x0080000] W1s 512K ; [0x0100000] W0t 64K
    // [0x0110000] S1 4K ; [0x0120000] h2cat 2M ; [0x0320000] Hc(f16) 16M
    // [0x1320000] W2t 16M  (h1cat 2M @0x1320000 and W1t 1M @0x1520000
    //                       overlay W2t region; dead before prep_w2t)
    char* base = (char*)d_ws;
    _Float16*       W1f   = (_Float16*)(base);
    _Float16*       W1s   = (_Float16*)(base + 0x80000);
    _Float16*       W0t   = (_Float16*)(base + 0x100000);
    float*          S1    = (float*)(base + 0x110000);
    unsigned short* h2cat = (unsigned short*)(base + 0x120000);
    _Float16*       Hc    = (_Float16*)(base + 0x320000);
    unsigned short* W2t   = (unsigned short*)(base + 0x1320000);
    unsigned short* h1cat = (unsigned short*)(base + 0x1320000);  // overlay
    unsigned short* W1t   = (unsigned short*)(base + 0x1520000);  // overlay

    prep_k<<<dim3(898), dim3(256), 0, stream>>>(d_W1, d_W0, m1_W1, m2_W1,
                                                W1f, W1s, W0t, S1, W1t);

    made1_k<<<dim3(16, 16), dim3(256), 0, stream>>>(x, m1_W0, m2_W0, m1_b0, m2_b0, h1cat);
    gemm2_k<<<dim3(16, 16), dim3(512), 0, stream>>>(h1cat, W1t, m1_b1, m2_b1, h2cat);

    prep_w2t_k<<<dim3(256, 32), dim3(256), 0, stream>>>(m1_W2, m2_W2, W2t);
    gemm3_k<<<dim3(64, 8), dim3(512), 0, stream>>>(h2cat, W2t, m1_b2, m2_b2, Hc);

    dimwise_k<<<dim3(4096), dim3(512), 0, stream>>>(Hc, x, t, W1f, W1s, W0t, S1,
                                                    d_W0, d_b0, d_b1, d_W2, d_b2,
                                                    (float*)d_out);
}

// Round 12
// 479.469 us; speedup vs baseline: 2.6015x; 2.6015x over previous
//
#include <hip/hip_runtime.h>
#include <math.h>

// B=1024, D=128, DH=64, H=512 ; rows = B*D = 131072
// Hc (bf16): [1024, 8192], Hc[b, k*128+d] = h[b,d,k]

typedef __attribute__((ext_vector_type(8))) short bf16x8;
typedef __attribute__((ext_vector_type(4))) float f32x4;

static __device__ __forceinline__ unsigned short f2bf(float f) {
    unsigned u = __builtin_bit_cast(unsigned, f);
    unsigned r = (u + 0x7FFFu + ((u >> 16) & 1u)) >> 16;
    return (unsigned short)r;
}
static __device__ __forceinline__ unsigned cvt_pk_bf16(float lo, float hi) {
    unsigned r;
    asm("v_cvt_pk_bf16_f32 %0, %1, %2" : "=v"(r) : "v"(lo), "v"(hi));
    return r;
}

static __device__ __forceinline__ float fexp2(float x) {
#if __has_builtin(__builtin_amdgcn_exp2f)
    return __builtin_amdgcn_exp2f(x);
#else
    float r; asm("v_exp_f32 %0, %1" : "=v"(r) : "v"(x)); return r;
#endif
}
static __device__ __forceinline__ float frcp(float x) {
#if __has_builtin(__builtin_amdgcn_rcpf)
    return __builtin_amdgcn_rcpf(x);
#else
    float r; asm("v_rcp_f32 %0, %1" : "=v"(r) : "v"(x)); return r;
#endif
}
// tanh(x) = 1 - 2/(1+e^{2x}); exp2-based, ~1e-6 abs err, saturates correctly.
static __device__ __forceinline__ float fast_tanh(float x) {
    const float e = fexp2(x * 2.8853900817779268f);   // e^{2x}
    const float r = frcp(1.f + e);
    return __builtin_fmaf(-2.f, r, 1.f);
}

// ---------------------------------------------------------------------------
// Merged prep: blocks [0,256) W1p ; [256,384) W0t ; [384,896) W1t. All bf16.
// W1p[n][k] = bf16(W1d[k][n]) ; W0t[n][k] = bf16(W0d[2+k][n]) ;
// W1t[n][k] = MADE-masked bf16 transpose of m1_W1/m2_W1.
// ---------------------------------------------------------------------------
__global__ __launch_bounds__(256, 4)
void prep_k(const float* __restrict__ W1d, const float* __restrict__ W0d,
            const float* __restrict__ W1a, const float* __restrict__ W1b,
            unsigned short* __restrict__ W1p, unsigned short* __restrict__ W0t,
            unsigned short* __restrict__ W1t)
{
    __shared__ float tile[32][33];
    const int bidx = blockIdx.x;
    const int tid  = threadIdx.x;

    if (bidx < 256) {
        const int n0 = (bidx & 15) * 32, k0 = (bidx >> 4) * 32;
        const int c = tid & 31, r4 = tid >> 5;
        #pragma unroll
        for (int i = 0; i < 4; ++i) {
            const int r = r4 * 4 + i;
            tile[r][c] = W1d[(k0 + r) * 512 + n0 + c];
        }
        __syncthreads();
        #pragma unroll
        for (int i = 0; i < 4; ++i) {
            const int r = r4 * 4 + i;
            W1p[(n0 + r) * 512 + k0 + c] = f2bf(tile[c][r]);
        }
    } else if (bidx < 384) {
        const int idx = (bidx - 256) * 256 + tid;     // 0..32767
        const int n = idx & 511, k = idx >> 9;
        W0t[n * 64 + k] = f2bf(W0d[(2 + k) * 512 + n]);
    } else {
        const int rel = bidx - 384;                   // 0..511
        const int n0 = (rel & 31) * 32;               // 0..1023
        const int k0 = (rel >> 5) * 32;               // 0..511
        const float* __restrict__ src = (n0 < 512) ? W1a : W1b;
        const int nrel0 = n0 & 511;
        const int c = tid & 31, r4 = tid >> 5;
        #pragma unroll
        for (int i = 0; i < 4; ++i) {
            const int r = r4 * 4 + i;
            tile[r][c] = src[(k0 + r) * 512 + nrel0 + c];
        }
        __syncthreads();
        #pragma unroll
        for (int i = 0; i < 4; ++i) {
            const int r = r4 * 4 + i;
            const int n = n0 + r;
            const int k = k0 + c;
            const bool keep = (k % 127) <= ((n & 511) % 127);
            W1t[(size_t)n * 512 + k] = keep ? f2bf(tile[c][r]) : (unsigned short)0;
        }
    }
}

// ---------------------------------------------------------------------------
// MADE layer 1, both nets: x[1024,128] @ (W0 .* mask1) -> h1cat bf16 [1024][1024]
// ---------------------------------------------------------------------------
__global__ __launch_bounds__(256, 4)
void made1_k(const float* __restrict__ x,
             const float* __restrict__ Wn1, const float* __restrict__ Wn2,
             const float* __restrict__ bn1, const float* __restrict__ bn2,
             unsigned short* __restrict__ h1cat)
{
    __shared__ float As[16][68];
    __shared__ float Bs[16][68];

    const int tid = threadIdx.x;
    const int bn  = blockIdx.x;          // 0..15 : net = bn>>3
    const int bm  = blockIdx.y;          // 0..15
    const int net = bn >> 3;
    const int nb  = (bn & 7) * 64;
    const int tx = tid & 15, ty = tid >> 4;
    const int m_base = bm * 64;

    const float* __restrict__ W  = net ? Wn2 : Wn1;
    const float* __restrict__ bi = net ? bn2 : bn1;

    float acc[4][4] = {};

    for (int k0 = 0; k0 < 128; k0 += 16) {
        {
            const int m  = tid >> 2;
            const int kk = (tid & 3) * 4;
            const float4 a4 = *reinterpret_cast<const float4*>(&x[(size_t)(m_base + m) * 128 + k0 + kk]);
            As[kk + 0][m] = a4.x; As[kk + 1][m] = a4.y;
            As[kk + 2][m] = a4.z; As[kk + 3][m] = a4.w;
        }
        {
            const int kk = tid >> 4;
            const int nn = (tid & 15) * 4;
            const int gk = k0 + kk;
            const int gn = nb + nn;
            float4 b4 = *reinterpret_cast<const float4*>(&W[gk * 512 + gn]);
            float bv[4] = {b4.x, b4.y, b4.z, b4.w};
            #pragma unroll
            for (int j = 0; j < 4; ++j) {
                const int n = gn + j;
                const bool keep = net ? ((127 - gk) <= (n % 127)) : (gk <= (n % 127));
                Bs[kk][nn + j] = keep ? bv[j] : 0.f;
            }
        }
        __syncthreads();
        #pragma unroll
        for (int kk = 0; kk < 16; ++kk) {
            const float4 a4 = *reinterpret_cast<const float4*>(&As[kk][ty * 4]);
            const float4 b4 = *reinterpret_cast<const float4*>(&Bs[kk][tx * 4]);
            const float av[4] = {a4.x, a4.y, a4.z, a4.w};
            const float bv[4] = {b4.x, b4.y, b4.z, b4.w};
            #pragma unroll
            for (int i = 0; i < 4; ++i)
                #pragma unroll
                for (int j = 0; j < 4; ++j)
                    acc[i][j] += av[i] * bv[j];
        }
        __syncthreads();
    }

    #pragma unroll
    for (int i = 0; i < 4; ++i) {
        const int m = m_base + ty * 4 + i;
        #pragma unroll
        for (int j = 0; j < 4; ++j) {
            const int n = nb + tx * 4 + j;
            const float v = fmaxf(acc[i][j] + bi[n], 0.f);
            h1cat[(size_t)m * 1024 + net * 512 + n] = f2bf(v);
        }
    }
}

// ---------------------------------------------------------------------------
// MADE W2 masked+transposed: W2t[n 0..8191][k 0..1023] bf16
// ---------------------------------------------------------------------------
__global__ __launch_bounds__(256, 4)
void prep_w2t_k(const float* __restrict__ W2a, const float* __restrict__ W2b,
                unsigned short* __restrict__ W2t)
{
    __shared__ float tile[32][33];
    const int tid = threadIdx.x;
    const int n0 = blockIdx.x * 32;      // 0..8191
    const int k0 = blockIdx.y * 32;      // 0..1023
    const float* __restrict__ src = (k0 < 512) ? W2a : W2b;
    const int krel0 = k0 & 511;
    const bool net1 = (k0 >= 512);
    const int c = tid & 31, r4 = tid >> 5;
    #pragma unroll
    for (int i = 0; i < 4; ++i) {
        const int r = r4 * 4 + i;        // k-offset
        tile[r][c] = src[(size_t)(krel0 + r) * 8192 + n0 + c];
    }
    __syncthreads();
    #pragma unroll
    for (int i = 0; i < 4; ++i) {
        const int r = r4 * 4 + i;        // n-offset
        const int n = n0 + r;
        const int k = k0 + c;
        const int km = (k & 511) % 127;
        const int dg = n & 127;
        const bool keep = net1 ? (km < 127 - dg) : (km < dg);
        W2t[(size_t)n * 1024 + k] = keep ? f2bf(tile[c][r]) : (unsigned short)0;
    }
}

// ---------------------------------------------------------------------------
// MADE layer 2: h2 = relu(h1 @ W1m + b). Barrier-free MFMA, tile 64x64.
// ---------------------------------------------------------------------------
__global__ __launch_bounds__(512, 2)
void gemm2_k(const unsigned short* __restrict__ h1cat,
             const unsigned short* __restrict__ W1t,
             const float* __restrict__ ba, const float* __restrict__ bb,
             unsigned short* __restrict__ h2cat)
{
    const int tid = threadIdx.x;
    const int n0 = blockIdx.x * 64;
    const int m0 = blockIdx.y * 64;
    const int lane = tid & 63, w = tid >> 6;
    const int l15 = lane & 15, l16 = lane >> 4;
    const int wm = w & 3, wn = w >> 2;
    const int net = n0 >> 9;
    const float* __restrict__ bi = net ? bb : ba;

    const unsigned short* Ab = h1cat + (size_t)(m0 + wm * 16 + l15) * 1024 + net * 512 + l16 * 8;
    const unsigned short* Bb = W1t + (size_t)(n0 + wn * 32 + l15) * 512 + l16 * 8;

    f32x4 acc[2] = {};
    bf16x8 a0, b0[2], a1, b1[2];
    a0 = *(const bf16x8*)(Ab);
    b0[0] = *(const bf16x8*)(Bb);
    b0[1] = *(const bf16x8*)(Bb + 16 * 512);

    #pragma unroll
    for (int s = 0; s < 15; ++s) {
        const int off = (s + 1) * 32;
        a1 = *(const bf16x8*)(Ab + off);
        b1[0] = *(const bf16x8*)(Bb + off);
        b1[1] = *(const bf16x8*)(Bb + 16 * 512 + off);
        acc[0] = __builtin_amdgcn_mfma_f32_16x16x32_bf16(a0, b0[0], acc[0], 0, 0, 0);
        acc[1] = __builtin_amdgcn_mfma_f32_16x16x32_bf16(a0, b0[1], acc[1], 0, 0, 0);
        a0 = a1; b0[0] = b1[0]; b0[1] = b1[1];
    }
    acc[0] = __builtin_amdgcn_mfma_f32_16x16x32_bf16(a0, b0[0], acc[0], 0, 0, 0);
    acc[1] = __builtin_amdgcn_mfma_f32_16x16x32_bf16(a0, b0[1], acc[1], 0, 0, 0);

    #pragma unroll
    for (int nt = 0; nt < 2; ++nt) {
        const int n = n0 + wn * 32 + nt * 16 + l15;
        const float bv = bi[n & 511];
        #pragma unroll
        for (int e = 0; e < 4; ++e) {
            const float v = fmaxf(acc[nt][e] + bv, 0.f);
            h2cat[(size_t)(m0 + wm * 16 + l16 * 4 + e) * 1024 + n] = f2bf(v);
        }
    }
}

// ---------------------------------------------------------------------------
// MADE layer 3 (r12-lean): tile 64m x 128n, 8 waves (2wm x 4wn), acc=16/thread
// -> ~76 regs -> 6 waves/SIMD (vs old ~2). K=1024, dist-1 prefetch.
// ---------------------------------------------------------------------------
__global__ __launch_bounds__(512, 4)
void gemm3_k(const unsigned short* __restrict__ h2cat,
             const unsigned short* __restrict__ W2t,
             const float* __restrict__ ba, const float* __restrict__ bb,
             unsigned short* __restrict__ Hc)
{
    const int tid = threadIdx.x;
    const int n0 = blockIdx.x * 128, m0 = blockIdx.y * 64;
    const int lane = tid & 63, w = tid >> 6;
    const int l15 = lane & 15, l16 = lane >> 4;
    const int wm = w & 1, wn = w >> 1;          // 2 x 4

    const unsigned short* Ab = h2cat + (size_t)(m0 + wm * 32 + l15) * 1024 + l16 * 8;
    const unsigned short* Bb = W2t + (size_t)(n0 + wn * 32 + l15) * 1024 + l16 * 8;

    f32x4 acc[2][2] = {};
    bf16x8 a0[2], b0[2], a1[2], b1[2];
    #pragma unroll
    for (int mt = 0; mt < 2; ++mt) a0[mt] = *(const bf16x8*)(Ab + mt * 16 * 1024);
    #pragma unroll
    for (int nt = 0; nt < 2; ++nt) b0[nt] = *(const bf16x8*)(Bb + nt * 16 * 1024);

    #pragma unroll 4
    for (int s = 0; s < 32; ++s) {
        if (s < 31) {
            const int off = (s + 1) * 32;
            #pragma unroll
            for (int mt = 0; mt < 2; ++mt) a1[mt] = *(const bf16x8*)(Ab + mt * 16 * 1024 + off);
            #pragma unroll
            for (int nt = 0; nt < 2; ++nt) b1[nt] = *(const bf16x8*)(Bb + nt * 16 * 1024 + off);
        }
        #pragma unroll
        for (int mt = 0; mt < 2; ++mt)
            #pragma unroll
            for (int nt = 0; nt < 2; ++nt)
                acc[mt][nt] = __builtin_amdgcn_mfma_f32_16x16x32_bf16(a0[mt], b0[nt], acc[mt][nt], 0, 0, 0);
        #pragma unroll
        for (int mt = 0; mt < 2; ++mt) a0[mt] = a1[mt];
        #pragma unroll
        for (int nt = 0; nt < 2; ++nt) b0[nt] = b1[nt];
    }

    #pragma unroll
    for (int nt = 0; nt < 2; ++nt) {
        const int n = n0 + wn * 32 + nt * 16 + l15;
        const float bsum = ba[n] + bb[n];
        #pragma unroll
        for (int mt = 0; mt < 2; ++mt) {
            const int mrow = m0 + wm * 32 + mt * 16 + l16 * 4;
            #pragma unroll
            for (int e = 0; e < 4; ++e)
                Hc[(size_t)(mrow + e) * 8192 + n] = f2bf(acc[mt][nt][e] + bsum);
        }
    }
}

// ---------------------------------------------------------------------------
// Fused dimwise MLP + exact JVP — r5 body verbatim; ONE change: launch_bounds
// min-waves 4 -> 3 (reg cap 128 -> ~170) to let the compiler hoist W1p loads
// deeper (ILP-over-TLP experiment; m97 ran at 164 VGPR / 3 waves per SIMD).
// LDS: zA [0,34816) tA [34816,69632) Hstage [69632,73728) xbuf [73728,73856)
// ---------------------------------------------------------------------------
__global__ __launch_bounds__(512, 3)
void dimwise_k(const unsigned short* __restrict__ Hc,
               const float* __restrict__ x, const float* __restrict__ t,
               const unsigned short* __restrict__ W1p, const unsigned short* __restrict__ W0t,
               const float* __restrict__ W0, const float* __restrict__ b0,
               const float* __restrict__ b1,
               const float* __restrict__ W2, const float* __restrict__ b2,
               float* __restrict__ out)
{
    __shared__ __align__(16) char smem[73856];

    const int tid  = threadIdx.x;
    // bijective XCD swizzle: 4 d-blocks of one batch row share an XCD L2.
    const int bid  = (blockIdx.x & 7) * 512 + (blockIdx.x >> 3);
    const int row0 = bid * 32;
    const int b    = row0 >> 7;
    const int d0   = row0 & 127;

    const int lane = tid & 63;
    const int w    = tid >> 6;          // wave 0..7, owns n in [w*64, w*64+64)
    const int l15 = lane & 15, l16 = lane >> 4;

    // ---- phase 0: stage Hc tile [32 row][64 k] (XOR-swizzled) + x ----
    if (tid < 256) {
        const int k    = tid >> 2;            // 0..63
        const int part = tid & 3;             // d offset part*8
        const bf16x8 hv = *(const bf16x8*)(Hc + (size_t)b * 8192 + k * 128 + d0 + part * 8);
        #pragma unroll
        for (int j = 0; j < 8; ++j) {
            const int row = part * 8 + j;
            const int byte = 69632 + row * 128 + ((2 * k) ^ ((row & 7) << 4));
            *(unsigned short*)(smem + byte) = (unsigned short)hv[j];
        }
    }
    if (tid < 32) ((float*)(smem + 73728))[tid] = x[b * 128 + d0 + tid];
    __syncthreads();

    // ---- phase 1: z1pre via SWAPPED MFMA (A=W0t rows=n, B=H cols=brow) ----
    f32x4 zacc[2][4] = {};   // [mt][nt]
    #pragma unroll
    for (int ks = 0; ks < 2; ++ks) {
        bf16x8 af[2];
        #pragma unroll
        for (int mt = 0; mt < 2; ++mt) {
            const int row = mt * 16 + l15;
            const int inner = (ks * 64 + l16 * 16) ^ ((l15 & 7) << 4);
            af[mt] = *(const bf16x8*)(smem + 69632 + row * 128 + inner);
        }
        #pragma unroll
        for (int nt = 0; nt < 4; ++nt) {
            const int n = w * 64 + nt * 16 + l15;
            const bf16x8 wf = *(const bf16x8*)(W0t + n * 64 + ks * 32 + l16 * 8);
            #pragma unroll
            for (int mt = 0; mt < 2; ++mt)
                zacc[mt][nt] = __builtin_amdgcn_mfma_f32_16x16x32_bf16(wf, af[mt], zacc[mt][nt], 0, 0, 0);
        }
    }
    {
        const float tv = t[0];
        const float* xb = (const float*)(smem + 73728);
        float xv[2];
        #pragma unroll
        for (int mt = 0; mt < 2; ++mt) xv[mt] = xb[mt * 16 + l15];
        #pragma unroll
        for (int nt = 0; nt < 4; ++nt) {
            const int nq = w * 64 + nt * 16 + l16 * 4;     // 4 consecutive n
            const float4 b04 = *(const float4*)&b0[nq];
            const float4 wr0 = *(const float4*)&W0[nq];
            const float4 wr1 = *(const float4*)&W0[512 + nq];
            const int kboff = (nq >> 3) * 272 + (nq & 7) * 2;
            #pragma unroll
            for (int mt = 0; mt < 2; ++mt) {
                float zq[4], sq[4];
                #pragma unroll
                for (int e = 0; e < 4; ++e) {
                    const float be  = (e == 0) ? b04.x : (e == 1) ? b04.y : (e == 2) ? b04.z : b04.w;
                    const float w0e = (e == 0) ? wr0.x : (e == 1) ? wr0.y : (e == 2) ? wr0.z : wr0.w;
                    const float w1e = (e == 0) ? wr1.x : (e == 1) ? wr1.y : (e == 2) ? wr1.z : wr1.w;
                    const float pre = zacc[mt][nt][e] + be + tv * w0e + xv[mt] * w1e;
                    const float z = fast_tanh(pre);
                    zq[e] = z;
                    sq[e] = (1.f - z * z) * w1e;
                }
                const int off = mt * 17408 + kboff + l15 * 16;
                *(uint2*)(smem + off)         = make_uint2(cvt_pk_bf16(zq[0], zq[1]), cvt_pk_bf16(zq[2], zq[3]));
                *(uint2*)(smem + 34816 + off) = make_uint2(cvt_pk_bf16(sq[0], sq[1]), cvt_pk_bf16(sq[2], sq[3]));
            }
        }
    }
    __syncthreads();

    // ---- phase 2: layer-1 GEMM (bf16 MFMA), fully unrolled, peeled tail ----
    const char* __restrict__ W1pc = (const char*)W1p;

    f32x4 accp[2][4] = {};
    f32x4 acct[2][4] = {};

    const int aoff0 = l15 * 16 + l16 * 272;
    const char* __restrict__ Wb = W1pc + (size_t)(w * 64 + l15) * 1024 + l16 * 16;

    bf16x8 za0[2], ta0[2], bf0[4];
    #pragma unroll
    for (int mt = 0; mt < 2; ++mt) {
        za0[mt] = *(const bf16x8*)(smem + mt * 17408 + aoff0);
        ta0[mt] = *(const bf16x8*)(smem + 34816 + mt * 17408 + aoff0);
    }
    #pragma unroll
    for (int nt = 0; nt < 4; ++nt)
        bf0[nt] = *(const bf16x8*)(Wb + nt * 16 * 1024);

    #pragma unroll
    for (int ks = 0; ks < 15; ++ks) {
        bf16x8 za1[2], ta1[2], bf1[4];
        const int aoff = aoff0 + (ks + 1) * 1088;
        #pragma unroll
        for (int mt = 0; mt < 2; ++mt) {
            za1[mt] = *(const bf16x8*)(smem + mt * 17408 + aoff);
            ta1[mt] = *(const bf16x8*)(smem + 34816 + mt * 17408 + aoff);
        }
        #pragma unroll
        for (int nt = 0; nt < 4; ++nt)
            bf1[nt] = *(const bf16x8*)(Wb + nt * 16 * 1024 + (ks + 1) * 64);
        #pragma unroll
        for (int mt = 0; mt < 2; ++mt)
            #pragma unroll
            for (int nt = 0; nt < 4; ++nt) {
                accp[mt][nt] = __builtin_amdgcn_mfma_f32_16x16x32_bf16(za0[mt], bf0[nt], accp[mt][nt], 0, 0, 0);
                acct[mt][nt] = __builtin_amdgcn_mfma_f32_16x16x32_bf16(ta0[mt], bf0[nt], acct[mt][nt], 0, 0, 0);
            }
        #pragma unroll
        for (int mt = 0; mt < 2; ++mt) { za0[mt] = za1[mt]; ta0[mt] = ta1[mt]; }
        #pragma unroll
        for (int nt = 0; nt < 4; ++nt) bf0[nt] = bf1[nt];
    }
    #pragma unroll
    for (int mt = 0; mt < 2; ++mt)
        #pragma unroll
        for (int nt = 0; nt < 4; ++nt) {
            accp[mt][nt] = __builtin_amdgcn_mfma_f32_16x16x32_bf16(za0[mt], bf0[nt], accp[mt][nt], 0, 0, 0);
            acct[mt][nt] = __builtin_amdgcn_mfma_f32_16x16x32_bf16(ta0[mt], bf0[nt], acct[mt][nt], 0, 0, 0);
        }

    // ---- phase 3: tanh/JVP epilogue + 512->1 dot ----
    float py[2][4] = {}, pj[2][4] = {};
    #pragma unroll
    for (int nt = 0; nt < 4; ++nt) {
        const int n = w * 64 + nt * 16 + l15;
        const float b1v = b1[n];
        const float w2v = W2[n];
        #pragma unroll
        for (int mt = 0; mt < 2; ++mt)
            #pragma unroll
            for (int e = 0; e < 4; ++e) {
                const float z2  = fast_tanh(accp[mt][nt][e] + b1v);
                const float dz2 = (1.f - z2 * z2) * acct[mt][nt][e];
                py[mt][e] += z2  * w2v;
                pj[mt][e] += dz2 * w2v;
            }
    }
    #pragma unroll
    for (int off = 1; off < 16; off <<= 1)
        #pragma unroll
        for (int mt = 0; mt < 2; ++mt)
            #pragma unroll
            for (int e = 0; e < 4; ++e) {
                py[mt][e] += __shfl_xor(py[mt][e], off);
                pj[mt][e] += __shfl_xor(pj[mt][e], off);
            }

    __syncthreads();
    float* part = (float*)smem;         // [8 w][2 mt][16 row][2]
    if (l15 == 0) {
        const int q = l16;
        #pragma unroll
        for (int mt = 0; mt < 2; ++mt)
            #pragma unroll
            for (int e = 0; e < 4; ++e) {
                const int idx = ((w * 2 + mt) * 16 + 4 * q + e) * 2;
                part[idx]     = py[mt][e];
                part[idx + 1] = pj[mt][e];
            }
    }
    __syncthreads();
    if (tid < 64) {
        const int mt = tid >> 5, row = (tid >> 1) & 15, wh = tid & 1;
        float s = 0.f;
        #pragma unroll
        for (int w8 = 0; w8 < 8; ++w8)
            s += part[((w8 * 2 + mt) * 16 + row) * 2 + wh];
        const int grow = row0 + mt * 16 + row;
        if (wh == 0) out[grow] = s + b2[0];
        else         out[131072 + grow] = s;
    }
}

// ---------------------------------------------------------------------------
extern "C" void kernel_launch(void* const* d_in, const int* in_sizes, int n_in,
                              void* d_out, int out_size, void* d_ws, size_t ws_size,
                              hipStream_t stream)
{
    (void)in_sizes; (void)n_in; (void)out_size; (void)ws_size;

    const float* t     = (const float*)d_in[0];
    const float* x     = (const float*)d_in[1];
    const float* m1_W0 = (const float*)d_in[2];
    const float* m1_b0 = (const float*)d_in[3];
    const float* m1_W1 = (const float*)d_in[4];
    const float* m1_b1 = (const float*)d_in[5];
    const float* m1_W2 = (const float*)d_in[6];
    const float* m1_b2 = (const float*)d_in[7];
    const float* m2_W0 = (const float*)d_in[8];
    const float* m2_b0 = (const float*)d_in[9];
    const float* m2_W1 = (const float*)d_in[10];
    const float* m2_b1 = (const float*)d_in[11];
    const float* m2_W2 = (const float*)d_in[12];
    const float* m2_b2 = (const float*)d_in[13];
    const float* d_W0  = (const float*)d_in[14];
    const float* d_b0  = (const float*)d_in[15];
    const float* d_W1  = (const float*)d_in[16];
    const float* d_b1  = (const float*)d_in[17];
    const float* d_W2  = (const float*)d_in[18];
    const float* d_b2  = (const float*)d_in[19];

    // ws layout (peak 36.25 MB):
    // [0x0000000] W1p   512K ; [0x0080000] W0t 64K ; [0x0090000] h2cat 2M
    // [0x0290000] Hc 16M ; [0x1290000] W2t 16M (h1cat/W1t overlay W2t region)
    char* base = (char*)d_ws;
    unsigned short* W1p   = (unsigned short*)(base);
    unsigned short* W0t   = (unsigned short*)(base + 0x80000);
    unsigned short* h2cat = (unsigned short*)(base + 0x90000);
    unsigned short* Hc    = (unsigned short*)(base + 0x290000);
    unsigned short* W2t   = (unsigned short*)(base + 0x1290000);
    unsigned short* h1cat = (unsigned short*)(base + 0x1290000);  // overlay
    unsigned short* W1t   = (unsigned short*)(base + 0x1490000);  // overlay

    prep_k<<<dim3(896), dim3(256), 0, stream>>>(d_W1, d_W0, m1_W1, m2_W1,
                                                W1p, W0t, W1t);

    made1_k<<<dim3(16, 16), dim3(256), 0, stream>>>(x, m1_W0, m2_W0, m1_b0, m2_b0, h1cat);
    gemm2_k<<<dim3(16, 16), dim3(512), 0, stream>>>(h1cat, W1t, m1_b1, m2_b1, h2cat);

    prep_w2t_k<<<dim3(256, 32), dim3(256), 0, stream>>>(m1_W2, m2_W2, W2t);
    gemm3_k<<<dim3(64, 16), dim3(512), 0, stream>>>(h2cat, W2t, m1_b2, m2_b2, Hc);

    dimwise_k<<<dim3(4096), dim3(512), 0, stream>>>(Hc, x, t, W1p, W0t,
                                                    d_W0, d_b0, d_b1, d_W2, d_b2,
                                                    (float*)d_out);
}

// Round 13
// 209.725 us; speedup vs baseline: 5.9475x; 2.2862x over previous
//
#include <hip/hip_runtime.h>
#include <math.h>

// B=1024, D=128, DH=64, H=512 ; rows = B*D = 131072
// Hc (bf16): [1024, 8192], Hc[b, k*128+d] = h[b,d,k]
//
// Fragment-packed layout for MFMA operands (16x16x32 bf16, row r, depth k):
//   elem_off P(r,k,NKS) = (((r>>4)*NKS + (k>>5))*64 + ((k>>3)&3)*16 + (r&15))*8 + (k&7)
// Consumer: wave loads byte = ((tile*NKS + ks)<<10) + lane*16  -> 1KB coalesced.

typedef __attribute__((ext_vector_type(8))) short bf16x8;
typedef __attribute__((ext_vector_type(4))) float f32x4;

static __device__ __forceinline__ unsigned short f2bf(float f) {
    unsigned u = __builtin_bit_cast(unsigned, f);
    unsigned r = (u + 0x7FFFu + ((u >> 16) & 1u)) >> 16;
    return (unsigned short)r;
}
static __device__ __forceinline__ unsigned cvt_pk_bf16(float lo, float hi) {
    unsigned r;
    asm("v_cvt_pk_bf16_f32 %0, %1, %2" : "=v"(r) : "v"(lo), "v"(hi));
    return r;
}
static __device__ __forceinline__ size_t packP(int r, int k, int NKS) {
    return ((((size_t)(r >> 4) * NKS + (k >> 5)) * 64 + ((k >> 3) & 3) * 16 + (r & 15)) << 3) + (k & 7);
}

static __device__ __forceinline__ float fexp2(float x) {
#if __has_builtin(__builtin_amdgcn_exp2f)
    return __builtin_amdgcn_exp2f(x);
#else
    float r; asm("v_exp_f32 %0, %1" : "=v"(r) : "v"(x)); return r;
#endif
}
static __device__ __forceinline__ float frcp(float x) {
#if __has_builtin(__builtin_amdgcn_rcpf)
    return __builtin_amdgcn_rcpf(x);
#else
    float r; asm("v_rcp_f32 %0, %1" : "=v"(r) : "v"(x)); return r;
#endif
}
// tanh(x) = 1 - 2/(1+e^{2x}); exp2-based, ~1e-6 abs err, saturates correctly.
static __device__ __forceinline__ float fast_tanh(float x) {
    const float e = fexp2(x * 2.8853900817779268f);   // e^{2x}
    const float r = frcp(1.f + e);
    return __builtin_fmaf(-2.f, r, 1.f);
}

// ---------------------------------------------------------------------------
// Merged prep: [0,256) W1q ; [256,384) W0q ; [384,896) W1tq. All bf16 packed.
// W1q: dimwise W1 transposed->packed (r=n, k, NKS=16)
// W0q: dimwise W0 h-rows -> packed (r=n 0..511, k 0..63, NKS=2)
// W1tq: MADE W1 masked+transposed -> packed (r=n 0..1023, k 0..511, NKS=16)
// ---------------------------------------------------------------------------
__global__ __launch_bounds__(256, 4)
void prep_k(const float* __restrict__ W1d, const float* __restrict__ W0d,
            const float* __restrict__ W1a, const float* __restrict__ W1b,
            unsigned short* __restrict__ W1q, unsigned short* __restrict__ W0q,
            unsigned short* __restrict__ W1tq)
{
    __shared__ float tile[32][33];
    const int bidx = blockIdx.x;
    const int tid  = threadIdx.x;

    if (bidx < 256) {
        const int n0 = (bidx & 15) * 32, k0 = (bidx >> 4) * 32;
        const int c = tid & 31, r4 = tid >> 5;
        #pragma unroll
        for (int i = 0; i < 4; ++i) {
            const int r = r4 * 4 + i;
            tile[r][c] = W1d[(k0 + r) * 512 + n0 + c];
        }
        __syncthreads();
        #pragma unroll
        for (int i = 0; i < 4; ++i) {
            const int r = r4 * 4 + i;
            W1q[packP(n0 + r, k0 + c, 16)] = f2bf(tile[c][r]);
        }
    } else if (bidx < 384) {
        const int idx = (bidx - 256) * 256 + tid;     // 0..32767
        const int n = idx & 511, k = idx >> 9;        // k 0..63
        W0q[packP(n, k, 2)] = f2bf(W0d[(2 + k) * 512 + n]);
    } else {
        const int rel = bidx - 384;                   // 0..511
        const int n0 = (rel & 31) * 32;               // 0..1023
        const int k0 = (rel >> 5) * 32;               // 0..511
        const float* __restrict__ src = (n0 < 512) ? W1a : W1b;
        const int nrel0 = n0 & 511;
        const int c = tid & 31, r4 = tid >> 5;
        #pragma unroll
        for (int i = 0; i < 4; ++i) {
            const int r = r4 * 4 + i;
            tile[r][c] = src[(k0 + r) * 512 + nrel0 + c];
        }
        __syncthreads();
        #pragma unroll
        for (int i = 0; i < 4; ++i) {
            const int r = r4 * 4 + i;
            const int n = n0 + r;
            const int k = k0 + c;
            const bool keep = (k % 127) <= ((n & 511) % 127);
            W1tq[packP(n, k, 16)] = keep ? f2bf(tile[c][r]) : (unsigned short)0;
        }
    }
}

// ---------------------------------------------------------------------------
// MADE layer 1, both nets: x @ (W0 .* mask1) -> A1q packed
// A1q tile index includes net: tileA = net*64 + (m>>4), NKS=16, k = within-net n
// ---------------------------------------------------------------------------
__global__ __launch_bounds__(256, 4)
void made1_k(const float* __restrict__ x,
             const float* __restrict__ Wn1, const float* __restrict__ Wn2,
             const float* __restrict__ bn1, const float* __restrict__ bn2,
             unsigned short* __restrict__ A1q)
{
    __shared__ float As[16][68];
    __shared__ float Bs[16][68];

    const int tid = threadIdx.x;
    const int bn  = blockIdx.x;          // 0..15 : net = bn>>3
    const int bm  = blockIdx.y;          // 0..15
    const int net = bn >> 3;
    const int nb  = (bn & 7) * 64;
    const int tx = tid & 15, ty = tid >> 4;
    const int m_base = bm * 64;

    const float* __restrict__ W  = net ? Wn2 : Wn1;
    const float* __restrict__ bi = net ? bn2 : bn1;

    float acc[4][4] = {};

    for (int k0 = 0; k0 < 128; k0 += 16) {
        {
            const int m  = tid >> 2;
            const int kk = (tid & 3) * 4;
            const float4 a4 = *reinterpret_cast<const float4*>(&x[(size_t)(m_base + m) * 128 + k0 + kk]);
            As[kk + 0][m] = a4.x; As[kk + 1][m] = a4.y;
            As[kk + 2][m] = a4.z; As[kk + 3][m] = a4.w;
        }
        {
            const int kk = tid >> 4;
            const int nn = (tid & 15) * 4;
            const int gk = k0 + kk;
            const int gn = nb + nn;
            float4 b4 = *reinterpret_cast<const float4*>(&W[gk * 512 + gn]);
            float bv[4] = {b4.x, b4.y, b4.z, b4.w};
            #pragma unroll
            for (int j = 0; j < 4; ++j) {
                const int n = gn + j;
                const bool keep = net ? ((127 - gk) <= (n % 127)) : (gk <= (n % 127));
                Bs[kk][nn + j] = keep ? bv[j] : 0.f;
            }
        }
        __syncthreads();
        #pragma unroll
        for (int kk = 0; kk < 16; ++kk) {
            const float4 a4 = *reinterpret_cast<const float4*>(&As[kk][ty * 4]);
            const float4 b4 = *reinterpret_cast<const float4*>(&Bs[kk][tx * 4]);
            const float av[4] = {a4.x, a4.y, a4.z, a4.w};
            const float bv[4] = {b4.x, b4.y, b4.z, b4.w};
            #pragma unroll
            for (int i = 0; i < 4; ++i)
                #pragma unroll
                for (int j = 0; j < 4; ++j)
                    acc[i][j] += av[i] * bv[j];
        }
        __syncthreads();
    }

    #pragma unroll
    for (int i = 0; i < 4; ++i) {
        const int m = m_base + ty * 4 + i;
        #pragma unroll
        for (int j = 0; j < 4; ++j) {
            const int n = nb + tx * 4 + j;             // within-net col = k
            const float v = fmaxf(acc[i][j] + bi[n], 0.f);
            const size_t off = ((((size_t)(net * 64 + (m >> 4)) * 16 + (n >> 5)) * 64
                               + ((n >> 3) & 3) * 16 + (m & 15)) << 3) + (n & 7);
            A1q[off] = f2bf(v);
        }
    }
}

// ---------------------------------------------------------------------------
// MADE W2 masked+transposed -> W2q packed (r=n 0..8191, k 0..1023, NKS=32)
// ---------------------------------------------------------------------------
__global__ __launch_bounds__(256, 4)
void prep_w2q_k(const float* __restrict__ W2a, const float* __restrict__ W2b,
                unsigned short* __restrict__ W2q)
{
    __shared__ float tile[32][33];
    const int tid = threadIdx.x;
    const int n0 = blockIdx.x * 32;      // 0..8191
    const int k0 = blockIdx.y * 32;      // 0..1023
    const float* __restrict__ src = (k0 < 512) ? W2a : W2b;
    const int krel0 = k0 & 511;
    const bool net1 = (k0 >= 512);
    const int c = tid & 31, r4 = tid >> 5;
    #pragma unroll
    for (int i = 0; i < 4; ++i) {
        const int r = r4 * 4 + i;        // k-offset
        tile[r][c] = src[(size_t)(krel0 + r) * 8192 + n0 + c];
    }
    __syncthreads();
    #pragma unroll
    for (int i = 0; i < 4; ++i) {
        const int r = r4 * 4 + i;        // n-offset
        const int n = n0 + r;
        const int k = k0 + c;
        const int km = (k & 511) % 127;
        const int dg = n & 127;
        const bool keep = net1 ? (km < 127 - dg) : (km < dg);
        W2q[packP(n, k, 32)] = keep ? f2bf(tile[c][r]) : (unsigned short)0;
    }
}

// ---------------------------------------------------------------------------
// MADE layer 2: A2q = pack(relu(h1 @ W1m + b)). Barrier-free MFMA, tile 64x64.
// A from A1q (packed), B from W1tq (packed); all loads 1KB-coalesced.
// ---------------------------------------------------------------------------
__global__ __launch_bounds__(512, 2)
void gemm2_k(const unsigned short* __restrict__ A1q,
             const unsigned short* __restrict__ W1tq,
             const float* __restrict__ ba, const float* __restrict__ bb,
             unsigned short* __restrict__ A2q)
{
    const int tid = threadIdx.x;
    const int n0 = blockIdx.x * 64;      // global col 0..1023
    const int m0 = blockIdx.y * 64;
    const int lane = tid & 63, w = tid >> 6;
    const int l15 = lane & 15, l16 = lane >> 4;
    const int wm = w & 3, wn = w >> 2;
    const int net = n0 >> 9;
    const float* __restrict__ bi = net ? bb : ba;

    const int mtileA = net * 64 + ((m0 + wm * 16) >> 4);
    const char* __restrict__ Ab = (const char*)A1q + (((size_t)mtileA * 16) << 10) + lane * 16;
    const int ntile0 = (n0 + wn * 32) >> 4;
    const char* __restrict__ Bb = (const char*)W1tq + (((size_t)ntile0 * 16) << 10) + lane * 16;

    f32x4 acc[2] = {};
    bf16x8 a0, b0[2], a1, b1[2];
    a0 = *(const bf16x8*)(Ab);
    b0[0] = *(const bf16x8*)(Bb);
    b0[1] = *(const bf16x8*)(Bb + 16 * 1024);   // next 16-col tile = +16 ks-slots

    #pragma unroll
    for (int s = 0; s < 15; ++s) {
        const int off = (s + 1) * 1024;
        a1 = *(const bf16x8*)(Ab + off);
        b1[0] = *(const bf16x8*)(Bb + off);
        b1[1] = *(const bf16x8*)(Bb + 16 * 1024 + off);
        acc[0] = __builtin_amdgcn_mfma_f32_16x16x32_bf16(a0, b0[0], acc[0], 0, 0, 0);
        acc[1] = __builtin_amdgcn_mfma_f32_16x16x32_bf16(a0, b0[1], acc[1], 0, 0, 0);
        a0 = a1; b0[0] = b1[0]; b0[1] = b1[1];
    }
    acc[0] = __builtin_amdgcn_mfma_f32_16x16x32_bf16(a0, b0[0], acc[0], 0, 0, 0);
    acc[1] = __builtin_amdgcn_mfma_f32_16x16x32_bf16(a0, b0[1], acc[1], 0, 0, 0);

    #pragma unroll
    for (int nt = 0; nt < 2; ++nt) {
        const int n = n0 + wn * 32 + nt * 16 + l15;   // global col 0..1023 = k of A2q
        const float bv = bi[n & 511];
        #pragma unroll
        for (int e = 0; e < 4; ++e) {
            const int r = m0 + wm * 16 + l16 * 4 + e;
            const float v = fmaxf(acc[nt][e] + bv, 0.f);
            const size_t off = ((((size_t)(r >> 4) * 32 + (n >> 5)) * 64
                               + ((n >> 3) & 3) * 16 + (r & 15)) << 3) + (n & 7);
            A2q[off] = f2bf(v);
        }
    }
}

// ---------------------------------------------------------------------------
// MADE layer 3, both nets fused over K=1024: Hc = A2q @ W2q^T + (b2a+b2b)
// r5 128x128 shape, packed coalesced loads. C-write row-major (unchanged).
// ---------------------------------------------------------------------------
__global__ __launch_bounds__(512, 2)
void gemm3_k(const unsigned short* __restrict__ A2q,
             const unsigned short* __restrict__ W2q,
             const float* __restrict__ ba, const float* __restrict__ bb,
             unsigned short* __restrict__ Hc)
{
    const int tid = threadIdx.x;
    const int n0 = blockIdx.x * 128, m0 = blockIdx.y * 128;
    const int lane = tid & 63, w = tid >> 6;
    const int l15 = lane & 15, l16 = lane >> 4;
    const int wm = w & 3, wn = w >> 2;

    const int mtile0 = (m0 + wm * 32) >> 4;           // +mt
    const int ntile0 = (n0 + wn * 64) >> 4;           // +nt
    const char* __restrict__ Ab = (const char*)A2q + (((size_t)mtile0 * 32) << 10) + lane * 16;
    const char* __restrict__ Bb = (const char*)W2q + (((size_t)ntile0 * 32) << 10) + lane * 16;

    f32x4 acc[2][4] = {};
    bf16x8 a0[2], b0[4], a1[2], b1[4];
    #pragma unroll
    for (int mt = 0; mt < 2; ++mt) a0[mt] = *(const bf16x8*)(Ab + mt * 32 * 1024);
    #pragma unroll
    for (int nt = 0; nt < 4; ++nt) b0[nt] = *(const bf16x8*)(Bb + nt * 32 * 1024);

    for (int s = 0; s < 32; ++s) {
        if (s < 31) {
            const int off = (s + 1) * 1024;
            #pragma unroll
            for (int mt = 0; mt < 2; ++mt) a1[mt] = *(const bf16x8*)(Ab + mt * 32 * 1024 + off);
            #pragma unroll
            for (int nt = 0; nt < 4; ++nt) b1[nt] = *(const bf16x8*)(Bb + nt * 32 * 1024 + off);
        }
        #pragma unroll
        for (int mt = 0; mt < 2; ++mt)
            #pragma unroll
            for (int nt = 0; nt < 4; ++nt)
                acc[mt][nt] = __builtin_amdgcn_mfma_f32_16x16x32_bf16(a0[mt], b0[nt], acc[mt][nt], 0, 0, 0);
        #pragma unroll
        for (int mt = 0; mt < 2; ++mt) a0[mt] = a1[mt];
        #pragma unroll
        for (int nt = 0; nt < 4; ++nt) b0[nt] = b1[nt];
    }

    #pragma unroll
    for (int nt = 0; nt < 4; ++nt) {
        const int n = n0 + wn * 64 + nt * 16 + l15;
        const float bsum = ba[n] + bb[n];
        #pragma unroll
        for (int mt = 0; mt < 2; ++mt) {
            const int mrow = m0 + wm * 32 + mt * 16 + l16 * 4;
            #pragma unroll
            for (int e = 0; e < 4; ++e)
                Hc[(size_t)(mrow + e) * 8192 + n] = f2bf(acc[mt][nt][e] + bsum);
        }
    }
}

// ---------------------------------------------------------------------------
// Fused dimwise MLP + exact JVP — r5 body verbatim; only the two B-operand
// address computations changed to the packed (coalesced) W1q/W0q layouts.
// LDS: zA [0,34816) tA [34816,69632) Hstage [69632,73728) xbuf [73728,73856)
// ---------------------------------------------------------------------------
__global__ __launch_bounds__(512, 4)
void dimwise_k(const unsigned short* __restrict__ Hc,
               const float* __restrict__ x, const float* __restrict__ t,
               const unsigned short* __restrict__ W1q, const unsigned short* __restrict__ W0q,
               const float* __restrict__ W0, const float* __restrict__ b0,
               const float* __restrict__ b1,
               const float* __restrict__ W2, const float* __restrict__ b2,
               float* __restrict__ out)
{
    __shared__ __align__(16) char smem[73856];

    const int tid  = threadIdx.x;
    // bijective XCD swizzle: 4 d-blocks of one batch row share an XCD L2.
    const int bid  = (blockIdx.x & 7) * 512 + (blockIdx.x >> 3);
    const int row0 = bid * 32;
    const int b    = row0 >> 7;
    const int d0   = row0 & 127;

    const int lane = tid & 63;
    const int w    = tid >> 6;          // wave 0..7, owns n in [w*64, w*64+64)
    const int l15 = lane & 15, l16 = lane >> 4;

    // ---- phase 0: stage Hc tile [32 row][64 k] (XOR-swizzled) + x ----
    if (tid < 256) {
        const int k    = tid >> 2;            // 0..63
        const int part = tid & 3;             // d offset part*8
        const bf16x8 hv = *(const bf16x8*)(Hc + (size_t)b * 8192 + k * 128 + d0 + part * 8);
        #pragma unroll
        for (int j = 0; j < 8; ++j) {
            const int row = part * 8 + j;
            const int byte = 69632 + row * 128 + ((2 * k) ^ ((row & 7) << 4));
            *(unsigned short*)(smem + byte) = (unsigned short)hv[j];
        }
    }
    if (tid < 32) ((float*)(smem + 73728))[tid] = x[b * 128 + d0 + tid];
    __syncthreads();

    // ---- phase 1: z1pre via SWAPPED MFMA (A=W0q rows=n, B=H cols=brow) ----
    f32x4 zacc[2][4] = {};   // [mt][nt]
    #pragma unroll
    for (int ks = 0; ks < 2; ++ks) {
        bf16x8 af[2];
        #pragma unroll
        for (int mt = 0; mt < 2; ++mt) {
            const int row = mt * 16 + l15;
            const int inner = (ks * 64 + l16 * 16) ^ ((l15 & 7) << 4);
            af[mt] = *(const bf16x8*)(smem + 69632 + row * 128 + inner);
        }
        #pragma unroll
        for (int nt = 0; nt < 4; ++nt) {
            const bf16x8 wf = *(const bf16x8*)((const char*)W0q
                              + ((((size_t)(w * 4 + nt) * 2 + ks)) << 10) + lane * 16);
            #pragma unroll
            for (int mt = 0; mt < 2; ++mt)
                zacc[mt][nt] = __builtin_amdgcn_mfma_f32_16x16x32_bf16(wf, af[mt], zacc[mt][nt], 0, 0, 0);
        }
    }
    {
        const float tv = t[0];
        const float* xb = (const float*)(smem + 73728);
        float xv[2];
        #pragma unroll
        for (int mt = 0; mt < 2; ++mt) xv[mt] = xb[mt * 16 + l15];
        #pragma unroll
        for (int nt = 0; nt < 4; ++nt) {
            const int nq = w * 64 + nt * 16 + l16 * 4;     // 4 consecutive n
            const float4 b04 = *(const float4*)&b0[nq];
            const float4 wr0 = *(const float4*)&W0[nq];
            const float4 wr1 = *(const float4*)&W0[512 + nq];
            const int kboff = (nq >> 3) * 272 + (nq & 7) * 2;
            #pragma unroll
            for (int mt = 0; mt < 2; ++mt) {
                float zq[4], sq[4];
                #pragma unroll
                for (int e = 0; e < 4; ++e) {
                    const float be  = (e == 0) ? b04.x : (e == 1) ? b04.y : (e == 2) ? b04.z : b04.w;
                    const float w0e = (e == 0) ? wr0.x : (e == 1) ? wr0.y : (e == 2) ? wr0.z : wr0.w;
                    const float w1e = (e == 0) ? wr1.x : (e == 1) ? wr1.y : (e == 2) ? wr1.z : wr1.w;
                    const float pre = zacc[mt][nt][e] + be + tv * w0e + xv[mt] * w1e;
                    const float z = fast_tanh(pre);
                    zq[e] = z;
                    sq[e] = (1.f - z * z) * w1e;
                }
                const int off = mt * 17408 + kboff + l15 * 16;
                *(uint2*)(smem + off)         = make_uint2(cvt_pk_bf16(zq[0], zq[1]), cvt_pk_bf16(zq[2], zq[3]));
                *(uint2*)(smem + 34816 + off) = make_uint2(cvt_pk_bf16(sq[0], sq[1]), cvt_pk_bf16(sq[2], sq[3]));
            }
        }
    }
    __syncthreads();

    // ---- phase 2: layer-1 GEMM (bf16 MFMA), fully unrolled, peeled tail ----
    f32x4 accp[2][4] = {};
    f32x4 acct[2][4] = {};

    const int aoff0 = l15 * 16 + l16 * 272;
    // packed W1q: tile = w*4+nt (NKS=16); per-nt stride 16<<10, per-ks 1<<10
    const char* __restrict__ Wb = (const char*)W1q + (((size_t)(w * 4) * 16) << 10) + lane * 16;

    bf16x8 za0[2], ta0[2], bf0[4];
    #pragma unroll
    for (int mt = 0; mt < 2; ++mt) {
        za0[mt] = *(const bf16x8*)(smem + mt * 17408 + aoff0);
        ta0[mt] = *(const bf16x8*)(smem + 34816 + mt * 17408 + aoff0);
    }
    #pragma unroll
    for (int nt = 0; nt < 4; ++nt)
        bf0[nt] = *(const bf16x8*)(Wb + nt * 16384);

    #pragma unroll
    for (int ks = 0; ks < 15; ++ks) {
        bf16x8 za1[2], ta1[2], bf1[4];
        const int aoff = aoff0 + (ks + 1) * 1088;
        #pragma unroll
        for (int mt = 0; mt < 2; ++mt) {
            za1[mt] = *(const bf16x8*)(smem + mt * 17408 + aoff);
            ta1[mt] = *(const bf16x8*)(smem + 34816 + mt * 17408 + aoff);
        }
        #pragma unroll
        for (int nt = 0; nt < 4; ++nt)
            bf1[nt] = *(const bf16x8*)(Wb + nt * 16384 + (ks + 1) * 1024);
        #pragma unroll
        for (int mt = 0; mt < 2; ++mt)
            #pragma unroll
            for (int nt = 0; nt < 4; ++nt) {
                accp[mt][nt] = __builtin_amdgcn_mfma_f32_16x16x32_bf16(za0[mt], bf0[nt], accp[mt][nt], 0, 0, 0);
                acct[mt][nt] = __builtin_amdgcn_mfma_f32_16x16x32_bf16(ta0[mt], bf0[nt], acct[mt][nt], 0, 0, 0);
            }
        #pragma unroll
        for (int mt = 0; mt < 2; ++mt) { za0[mt] = za1[mt]; ta0[mt] = ta1[mt]; }
        #pragma unroll
        for (int nt = 0; nt < 4; ++nt) bf0[nt] = bf1[nt];
    }
    #pragma unroll
    for (int mt = 0; mt < 2; ++mt)
        #pragma unroll
        for (int nt = 0; nt < 4; ++nt) {
            accp[mt][nt] = __builtin_amdgcn_mfma_f32_16x16x32_bf16(za0[mt], bf0[nt], accp[mt][nt], 0, 0, 0);
            acct[mt][nt] = __builtin_amdgcn_mfma_f32_16x16x32_bf16(ta0[mt], bf0[nt], acct[mt][nt], 0, 0, 0);
        }

    // ---- phase 3: tanh/JVP epilogue + 512->1 dot ----
    float py[2][4] = {}, pj[2][4] = {};
    #pragma unroll
    for (int nt = 0; nt < 4; ++nt) {
        const int n = w * 64 + nt * 16 + l15;
        const float b1v = b1[n];
        const float w2v = W2[n];
        #pragma unroll
        for (int mt = 0; mt < 2; ++mt)
            #pragma unroll
            for (int e = 0; e < 4; ++e) {
                const float z2  = fast_tanh(accp[mt][nt][e] + b1v);
                const float dz2 = (1.f - z2 * z2) * acct[mt][nt][e];
                py[mt][e] += z2  * w2v;
                pj[mt][e] += dz2 * w2v;
            }
    }
    #pragma unroll
    for (int off = 1; off < 16; off <<= 1)
        #pragma unroll
        for (int mt = 0; mt < 2; ++mt)
            #pragma unroll
            for (int e = 0; e < 4; ++e) {
                py[mt][e] += __shfl_xor(py[mt][e], off);
                pj[mt][e] += __shfl_xor(pj[mt][e], off);
            }

    __syncthreads();
    float* part = (float*)smem;         // [8 w][2 mt][16 row][2]
    if (l15 == 0) {
        const int q = l16;
        #pragma unroll
        for (int mt = 0; mt < 2; ++mt)
            #pragma unroll
            for (int e = 0; e < 4; ++e) {
                const int idx = ((w * 2 + mt) * 16 + 4 * q + e) * 2;
                part[idx]     = py[mt][e];
                part[idx + 1] = pj[mt][e];
            }
    }
    __syncthreads();
    if (tid < 64) {
        const int mt = tid >> 5, row = (tid >> 1) & 15, wh = tid & 1;
        float s = 0.f;
        #pragma unroll
        for (int w8 = 0; w8 < 8; ++w8)
            s += part[((w8 * 2 + mt) * 16 + row) * 2 + wh];
        const int grow = row0 + mt * 16 + row;
        if (wh == 0) out[grow] = s + b2[0];
        else         out[131072 + grow] = s;
    }
}

// ---------------------------------------------------------------------------
extern "C" void kernel_launch(void* const* d_in, const int* in_sizes, int n_in,
                              void* d_out, int out_size, void* d_ws, size_t ws_size,
                              hipStream_t stream)
{
    (void)in_sizes; (void)n_in; (void)out_size; (void)ws_size;

    const float* t     = (const float*)d_in[0];
    const float* x     = (const float*)d_in[1];
    const float* m1_W0 = (const float*)d_in[2];
    const float* m1_b0 = (const float*)d_in[3];
    const float* m1_W1 = (const float*)d_in[4];
    const float* m1_b1 = (const float*)d_in[5];
    const float* m1_W2 = (const float*)d_in[6];
    const float* m1_b2 = (const float*)d_in[7];
    const float* m2_W0 = (const float*)d_in[8];
    const float* m2_b0 = (const float*)d_in[9];
    const float* m2_W1 = (const float*)d_in[10];
    const float* m2_b1 = (const float*)d_in[11];
    const float* m2_W2 = (const float*)d_in[12];
    const float* m2_b2 = (const float*)d_in[13];
    const float* d_W0  = (const float*)d_in[14];
    const float* d_b0  = (const float*)d_in[15];
    const float* d_W1  = (const float*)d_in[16];
    const float* d_b1  = (const float*)d_in[17];
    const float* d_W2  = (const float*)d_in[18];
    const float* d_b2  = (const float*)d_in[19];

    // ws layout (peak 0x2290000 = 36.25 MB, r5-proven size):
    // [0x0000000] W1q 512K ; [0x0080000] W0q 64K
    // [0x0090000] Hc 16M (overlays W1tq 1M @0x90000 + A1q 2M @0x190000,
    //                     both dead before gemm3 writes Hc)
    // [0x1090000] A2q 2M ; [0x1290000] W2q 16M
    char* base = (char*)d_ws;
    unsigned short* W1q  = (unsigned short*)(base);
    unsigned short* W0q  = (unsigned short*)(base + 0x80000);
    unsigned short* Hc   = (unsigned short*)(base + 0x90000);
    unsigned short* W1tq = (unsigned short*)(base + 0x90000);    // overlay
    unsigned short* A1q  = (unsigned short*)(base + 0x190000);   // overlay
    unsigned short* A2q  = (unsigned short*)(base + 0x1090000);
    unsigned short* W2q  = (unsigned short*)(base + 0x1290000);

    prep_k<<<dim3(896), dim3(256), 0, stream>>>(d_W1, d_W0, m1_W1, m2_W1,
                                                W1q, W0q, W1tq);

    made1_k<<<dim3(16, 16), dim3(256), 0, stream>>>(x, m1_W0, m2_W0, m1_b0, m2_b0, A1q);
    gemm2_k<<<dim3(16, 16), dim3(512), 0, stream>>>(A1q, W1tq, m1_b1, m2_b1, A2q);

    prep_w2q_k<<<dim3(256, 32), dim3(256), 0, stream>>>(m1_W2, m2_W2, W2q);
    gemm3_k<<<dim3(64, 8), dim3(512), 0, stream>>>(A2q, W2q, m1_b2, m2_b2, Hc);

    dimwise_k<<<dim3(4096), dim3(512), 0, stream>>>(Hc, x, t, W1q, W0q,
                                                    d_W0, d_b0, d_b1, d_W2, d_b2,
                                                    (float*)d_out);
}

// Round 14
// 205.441 us; speedup vs baseline: 6.0715x; 1.0209x over previous
//
#include <hip/hip_runtime.h>
#include <math.h>

// B=1024, D=128, DH=64, H=512 ; rows = B*D = 131072
// Hc (bf16): [1024, 8192], Hc[b, k*128+d] = h[b,d,k]
//
// Fragment-packed layout for MFMA operands (16x16x32 bf16, row r, depth k):
//   elem_off P(r,k,NKS) = (((r>>4)*NKS + (k>>5))*64 + ((k>>3)&3)*16 + (r&15))*8 + (k&7)
// Consumer: wave loads byte = ((tile*NKS + ks)<<10) + lane*16  -> 1KB coalesced.

typedef __attribute__((ext_vector_type(8))) short bf16x8;
typedef __attribute__((ext_vector_type(4))) float f32x4;

static __device__ __forceinline__ unsigned short f2bf(float f) {
    unsigned u = __builtin_bit_cast(unsigned, f);
    unsigned r = (u + 0x7FFFu + ((u >> 16) & 1u)) >> 16;
    return (unsigned short)r;
}
static __device__ __forceinline__ unsigned cvt_pk_bf16(float lo, float hi) {
    unsigned r;
    asm("v_cvt_pk_bf16_f32 %0, %1, %2" : "=v"(r) : "v"(lo), "v"(hi));
    return r;
}
static __device__ __forceinline__ size_t packP(int r, int k, int NKS) {
    return ((((size_t)(r >> 4) * NKS + (k >> 5)) * 64 + ((k >> 3) & 3) * 16 + (r & 15)) << 3) + (k & 7);
}

static __device__ __forceinline__ float fexp2(float x) {
#if __has_builtin(__builtin_amdgcn_exp2f)
    return __builtin_amdgcn_exp2f(x);
#else
    float r; asm("v_exp_f32 %0, %1" : "=v"(r) : "v"(x)); return r;
#endif
}
static __device__ __forceinline__ float frcp(float x) {
#if __has_builtin(__builtin_amdgcn_rcpf)
    return __builtin_amdgcn_rcpf(x);
#else
    float r; asm("v_rcp_f32 %0, %1" : "=v"(r) : "v"(x)); return r;
#endif
}
// tanh(x) = 1 - 2/(1+e^{2x}); exp2-based, ~1e-6 abs err, saturates correctly.
static __device__ __forceinline__ float fast_tanh(float x) {
    const float e = fexp2(x * 2.8853900817779268f);   // e^{2x}
    const float r = frcp(1.f + e);
    return __builtin_fmaf(-2.f, r, 1.f);
}

// ---------------------------------------------------------------------------
// Merged prework (ALL independent pre-GEMM work in ONE launch):
//  blocks [0, 8192)        : W2q  (MADE W2 masked+transposed packed, NKS=32)
//  blocks [8192, 9088)     : prep_k (W1q / W0q / W1tq)
//  blocks [9088, 9344)     : made1 (x @ masked-W0 -> A1q packed)
// ---------------------------------------------------------------------------
__global__ __launch_bounds__(256, 4)
void prework_k(const float* __restrict__ W1d, const float* __restrict__ W0d,
               const float* __restrict__ W1a, const float* __restrict__ W1b,
               const float* __restrict__ W2a, const float* __restrict__ W2b,
               const float* __restrict__ x,
               const float* __restrict__ m1W0, const float* __restrict__ m2W0,
               const float* __restrict__ b0a, const float* __restrict__ b0b,
               unsigned short* __restrict__ W1q, unsigned short* __restrict__ W0q,
               unsigned short* __restrict__ W1tq, unsigned short* __restrict__ W2q,
               unsigned short* __restrict__ A1q)
{
    __shared__ float shbuf[2176];                 // 8704 B: max of all branches
    const int bidx = blockIdx.x;
    const int tid  = threadIdx.x;

    if (bidx < 8192) {
        // ---- W2q: masked+transposed pack (r=n 0..8191, k 0..1023, NKS=32) ----
        float (*tile)[33] = (float(*)[33])shbuf;
        const int n0 = (bidx & 255) * 32;
        const int k0 = (bidx >> 8) * 32;
        const float* __restrict__ src = (k0 < 512) ? W2a : W2b;
        const int krel0 = k0 & 511;
        const bool net1 = (k0 >= 512);
        const int c = tid & 31, r4 = tid >> 5;
        #pragma unroll
        for (int i = 0; i < 4; ++i) {
            const int r = r4 * 4 + i;             // k-offset
            tile[r][c] = src[(size_t)(krel0 + r) * 8192 + n0 + c];
        }
        __syncthreads();
        #pragma unroll
        for (int i = 0; i < 4; ++i) {
            const int r = r4 * 4 + i;             // n-offset
            const int n = n0 + r;
            const int k = k0 + c;
            const int km = (k & 511) % 127;
            const int dg = n & 127;
            const bool keep = net1 ? (km < 127 - dg) : (km < dg);
            W2q[packP(n, k, 32)] = keep ? f2bf(tile[c][r]) : (unsigned short)0;
        }
    } else if (bidx < 9088) {
        const int rel = bidx - 8192;
        float (*tile)[33] = (float(*)[33])shbuf;
        if (rel < 256) {
            // ---- W1q: dimwise W1 transposed packed (NKS=16) ----
            const int n0 = (rel & 15) * 32, k0 = (rel >> 4) * 32;
            const int c = tid & 31, r4 = tid >> 5;
            #pragma unroll
            for (int i = 0; i < 4; ++i) {
                const int r = r4 * 4 + i;
                tile[r][c] = W1d[(k0 + r) * 512 + n0 + c];
            }
            __syncthreads();
            #pragma unroll
            for (int i = 0; i < 4; ++i) {
                const int r = r4 * 4 + i;
                W1q[packP(n0 + r, k0 + c, 16)] = f2bf(tile[c][r]);
            }
        } else if (rel < 384) {
            // ---- W0q: dimwise W0 h-rows packed (r=n, k 0..63, NKS=2) ----
            const int idx = (rel - 256) * 256 + tid;   // 0..32767
            const int n = idx & 511, k = idx >> 9;
            W0q[packP(n, k, 2)] = f2bf(W0d[(2 + k) * 512 + n]);
        } else {
            // ---- W1tq: MADE W1 masked+transposed packed (NKS=16) ----
            const int rr = rel - 384;                  // 0..511
            const int n0 = (rr & 31) * 32;             // 0..1023
            const int k0 = (rr >> 5) * 32;             // 0..511
            const float* __restrict__ src = (n0 < 512) ? W1a : W1b;
            const int nrel0 = n0 & 511;
            const int c = tid & 31, r4 = tid >> 5;
            #pragma unroll
            for (int i = 0; i < 4; ++i) {
                const int r = r4 * 4 + i;
                tile[r][c] = src[(k0 + r) * 512 + nrel0 + c];
            }
            __syncthreads();
            #pragma unroll
            for (int i = 0; i < 4; ++i) {
                const int r = r4 * 4 + i;
                const int n = n0 + r;
                const int k = k0 + c;
                const bool keep = (k % 127) <= ((n & 511) % 127);
                W1tq[packP(n, k, 16)] = keep ? f2bf(tile[c][r]) : (unsigned short)0;
            }
        }
    } else {
        // ---- made1: x @ (W0 .* mask1) -> A1q packed (relu) ----
        const int mb = bidx - 9088;
        const int bn = mb & 15;              // net = bn>>3
        const int bm = mb >> 4;
        float (*As)[68] = (float(*)[68])shbuf;
        float (*Bs)[68] = (float(*)[68])(shbuf + 1088);

        const int net = bn >> 3;
        const int nb  = (bn & 7) * 64;
        const int tx = tid & 15, ty = tid >> 4;
        const int m_base = bm * 64;

        const float* __restrict__ W  = net ? m2W0 : m1W0;
        const float* __restrict__ bi = net ? b0b : b0a;

        float acc[4][4] = {};

        for (int k0 = 0; k0 < 128; k0 += 16) {
            {
                const int m  = tid >> 2;
                const int kk = (tid & 3) * 4;
                const float4 a4 = *reinterpret_cast<const float4*>(&x[(size_t)(m_base + m) * 128 + k0 + kk]);
                As[kk + 0][m] = a4.x; As[kk + 1][m] = a4.y;
                As[kk + 2][m] = a4.z; As[kk + 3][m] = a4.w;
            }
            {
                const int kk = tid >> 4;
                const int nn = (tid & 15) * 4;
                const int gk = k0 + kk;
                const int gn = nb + nn;
                float4 b4 = *reinterpret_cast<const float4*>(&W[gk * 512 + gn]);
                float bv[4] = {b4.x, b4.y, b4.z, b4.w};
                #pragma unroll
                for (int j = 0; j < 4; ++j) {
                    const int n = gn + j;
                    const bool keep = net ? ((127 - gk) <= (n % 127)) : (gk <= (n % 127));
                    Bs[kk][nn + j] = keep ? bv[j] : 0.f;
                }
            }
            __syncthreads();
            #pragma unroll
            for (int kk = 0; kk < 16; ++kk) {
                const float4 a4 = *reinterpret_cast<const float4*>(&As[kk][ty * 4]);
                const float4 b4 = *reinterpret_cast<const float4*>(&Bs[kk][tx * 4]);
                const float av[4] = {a4.x, a4.y, a4.z, a4.w};
                const float bv[4] = {b4.x, b4.y, b4.z, b4.w};
                #pragma unroll
                for (int i = 0; i < 4; ++i)
                    #pragma unroll
                    for (int j = 0; j < 4; ++j)
                        acc[i][j] += av[i] * bv[j];
            }
            __syncthreads();
        }

        #pragma unroll
        for (int i = 0; i < 4; ++i) {
            const int m = m_base + ty * 4 + i;
            #pragma unroll
            for (int j = 0; j < 4; ++j) {
                const int n = nb + tx * 4 + j;             // within-net col = k
                const float v = fmaxf(acc[i][j] + bi[n], 0.f);
                const size_t off = ((((size_t)(net * 64 + (m >> 4)) * 16 + (n >> 5)) * 64
                                   + ((n >> 3) & 3) * 16 + (m & 15)) << 3) + (n & 7);
                A1q[off] = f2bf(v);
            }
        }
    }
}

// ---------------------------------------------------------------------------
// MADE layer 2: A2q = pack(relu(h1 @ W1m + b)). Barrier-free MFMA, tile 64x64.
// ---------------------------------------------------------------------------
__global__ __launch_bounds__(512, 2)
void gemm2_k(const unsigned short* __restrict__ A1q,
             const unsigned short* __restrict__ W1tq,
             const float* __restrict__ ba, const float* __restrict__ bb,
             unsigned short* __restrict__ A2q)
{
    const int tid = threadIdx.x;
    const int n0 = blockIdx.x * 64;      // global col 0..1023
    const int m0 = blockIdx.y * 64;
    const int lane = tid & 63, w = tid >> 6;
    const int l15 = lane & 15, l16 = lane >> 4;
    const int wm = w & 3, wn = w >> 2;
    const int net = n0 >> 9;
    const float* __restrict__ bi = net ? bb : ba;

    const int mtileA = net * 64 + ((m0 + wm * 16) >> 4);
    const char* __restrict__ Ab = (const char*)A1q + (((size_t)mtileA * 16) << 10) + lane * 16;
    const int ntile0 = (n0 + wn * 32) >> 4;
    const char* __restrict__ Bb = (const char*)W1tq + (((size_t)ntile0 * 16) << 10) + lane * 16;

    f32x4 acc[2] = {};
    bf16x8 a0, b0[2], a1, b1[2];
    a0 = *(const bf16x8*)(Ab);
    b0[0] = *(const bf16x8*)(Bb);
    b0[1] = *(const bf16x8*)(Bb + 16 * 1024);

    #pragma unroll
    for (int s = 0; s < 15; ++s) {
        const int off = (s + 1) * 1024;
        a1 = *(const bf16x8*)(Ab + off);
        b1[0] = *(const bf16x8*)(Bb + off);
        b1[1] = *(const bf16x8*)(Bb + 16 * 1024 + off);
        acc[0] = __builtin_amdgcn_mfma_f32_16x16x32_bf16(a0, b0[0], acc[0], 0, 0, 0);
        acc[1] = __builtin_amdgcn_mfma_f32_16x16x32_bf16(a0, b0[1], acc[1], 0, 0, 0);
        a0 = a1; b0[0] = b1[0]; b0[1] = b1[1];
    }
    acc[0] = __builtin_amdgcn_mfma_f32_16x16x32_bf16(a0, b0[0], acc[0], 0, 0, 0);
    acc[1] = __builtin_amdgcn_mfma_f32_16x16x32_bf16(a0, b0[1], acc[1], 0, 0, 0);

    #pragma unroll
    for (int nt = 0; nt < 2; ++nt) {
        const int n = n0 + wn * 32 + nt * 16 + l15;   // global col = k of A2q
        const float bv = bi[n & 511];
        #pragma unroll
        for (int e = 0; e < 4; ++e) {
            const int r = m0 + wm * 16 + l16 * 4 + e;
            const float v = fmaxf(acc[nt][e] + bv, 0.f);
            const size_t off = ((((size_t)(r >> 4) * 32 + (n >> 5)) * 64
                               + ((n >> 3) & 3) * 16 + (r & 15)) << 3) + (n & 7);
            A2q[off] = f2bf(v);
        }
    }
}

// ---------------------------------------------------------------------------
// MADE layer 3, both nets fused over K=1024: Hc = A2q @ W2q^T + (b2a+b2b)
// ---------------------------------------------------------------------------
__global__ __launch_bounds__(512, 2)
void gemm3_k(const unsigned short* __restrict__ A2q,
             const unsigned short* __restrict__ W2q,
             const float* __restrict__ ba, const float* __restrict__ bb,
             unsigned short* __restrict__ Hc)
{
    const int tid = threadIdx.x;
    const int n0 = blockIdx.x * 128, m0 = blockIdx.y * 128;
    const int lane = tid & 63, w = tid >> 6;
    const int l15 = lane & 15, l16 = lane >> 4;
    const int wm = w & 3, wn = w >> 2;

    const int mtile0 = (m0 + wm * 32) >> 4;
    const int ntile0 = (n0 + wn * 64) >> 4;
    const char* __restrict__ Ab = (const char*)A2q + (((size_t)mtile0 * 32) << 10) + lane * 16;
    const char* __restrict__ Bb = (const char*)W2q + (((size_t)ntile0 * 32) << 10) + lane * 16;

    f32x4 acc[2][4] = {};
    bf16x8 a0[2], b0[4], a1[2], b1[4];
    #pragma unroll
    for (int mt = 0; mt < 2; ++mt) a0[mt] = *(const bf16x8*)(Ab + mt * 32 * 1024);
    #pragma unroll
    for (int nt = 0; nt < 4; ++nt) b0[nt] = *(const bf16x8*)(Bb + nt * 32 * 1024);

    for (int s = 0; s < 32; ++s) {
        if (s < 31) {
            const int off = (s + 1) * 1024;
            #pragma unroll
            for (int mt = 0; mt < 2; ++mt) a1[mt] = *(const bf16x8*)(Ab + mt * 32 * 1024 + off);
            #pragma unroll
            for (int nt = 0; nt < 4; ++nt) b1[nt] = *(const bf16x8*)(Bb + nt * 32 * 1024 + off);
        }
        #pragma unroll
        for (int mt = 0; mt < 2; ++mt)
            #pragma unroll
            for (int nt = 0; nt < 4; ++nt)
                acc[mt][nt] = __builtin_amdgcn_mfma_f32_16x16x32_bf16(a0[mt], b0[nt], acc[mt][nt], 0, 0, 0);
        #pragma unroll
        for (int mt = 0; mt < 2; ++mt) a0[mt] = a1[mt];
        #pragma unroll
        for (int nt = 0; nt < 4; ++nt) b0[nt] = b1[nt];
    }

    #pragma unroll
    for (int nt = 0; nt < 4; ++nt) {
        const int n = n0 + wn * 64 + nt * 16 + l15;
        const float bsum = ba[n] + bb[n];
        #pragma unroll
        for (int mt = 0; mt < 2; ++mt) {
            const int mrow = m0 + wm * 32 + mt * 16 + l16 * 4;
            #pragma unroll
            for (int e = 0; e < 4; ++e)
                Hc[(size_t)(mrow + e) * 8192 + n] = f2bf(acc[mt][nt][e] + bsum);
        }
    }
}

// ---------------------------------------------------------------------------
// Fused dimwise MLP + exact JVP — r13 verbatim (proven 158 us).
// LDS: zA [0,34816) tA [34816,69632) Hstage [69632,73728) xbuf [73728,73856)
// ---------------------------------------------------------------------------
__global__ __launch_bounds__(512, 4)
void dimwise_k(const unsigned short* __restrict__ Hc,
               const float* __restrict__ x, const float* __restrict__ t,
               const unsigned short* __restrict__ W1q, const unsigned short* __restrict__ W0q,
               const float* __restrict__ W0, const float* __restrict__ b0,
               const float* __restrict__ b1,
               const float* __restrict__ W2, const float* __restrict__ b2,
               float* __restrict__ out)
{
    __shared__ __align__(16) char smem[73856];

    const int tid  = threadIdx.x;
    // bijective XCD swizzle: 4 d-blocks of one batch row share an XCD L2.
    const int bid  = (blockIdx.x & 7) * 512 + (blockIdx.x >> 3);
    const int row0 = bid * 32;
    const int b    = row0 >> 7;
    const int d0   = row0 & 127;

    const int lane = tid & 63;
    const int w    = tid >> 6;          // wave 0..7, owns n in [w*64, w*64+64)
    const int l15 = lane & 15, l16 = lane >> 4;

    // ---- phase 0: stage Hc tile [32 row][64 k] (XOR-swizzled) + x ----
    if (tid < 256) {
        const int k    = tid >> 2;            // 0..63
        const int part = tid & 3;             // d offset part*8
        const bf16x8 hv = *(const bf16x8*)(Hc + (size_t)b * 8192 + k * 128 + d0 + part * 8);
        #pragma unroll
        for (int j = 0; j < 8; ++j) {
            const int row = part * 8 + j;
            const int byte = 69632 + row * 128 + ((2 * k) ^ ((row & 7) << 4));
            *(unsigned short*)(smem + byte) = (unsigned short)hv[j];
        }
    }
    if (tid < 32) ((float*)(smem + 73728))[tid] = x[b * 128 + d0 + tid];
    __syncthreads();

    // ---- phase 1: z1pre via SWAPPED MFMA (A=W0q rows=n, B=H cols=brow) ----
    f32x4 zacc[2][4] = {};   // [mt][nt]
    #pragma unroll
    for (int ks = 0; ks < 2; ++ks) {
        bf16x8 af[2];
        #pragma unroll
        for (int mt = 0; mt < 2; ++mt) {
            const int row = mt * 16 + l15;
            const int inner = (ks * 64 + l16 * 16) ^ ((l15 & 7) << 4);
            af[mt] = *(const bf16x8*)(smem + 69632 + row * 128 + inner);
        }
        #pragma unroll
        for (int nt = 0; nt < 4; ++nt) {
            const bf16x8 wf = *(const bf16x8*)((const char*)W0q
                              + ((((size_t)(w * 4 + nt) * 2 + ks)) << 10) + lane * 16);
            #pragma unroll
            for (int mt = 0; mt < 2; ++mt)
                zacc[mt][nt] = __builtin_amdgcn_mfma_f32_16x16x32_bf16(wf, af[mt], zacc[mt][nt], 0, 0, 0);
        }
    }
    {
        const float tv = t[0];
        const float* xb = (const float*)(smem + 73728);
        float xv[2];
        #pragma unroll
        for (int mt = 0; mt < 2; ++mt) xv[mt] = xb[mt * 16 + l15];
        #pragma unroll
        for (int nt = 0; nt < 4; ++nt) {
            const int nq = w * 64 + nt * 16 + l16 * 4;     // 4 consecutive n
            const float4 b04 = *(const float4*)&b0[nq];
            const float4 wr0 = *(const float4*)&W0[nq];
            const float4 wr1 = *(const float4*)&W0[512 + nq];
            const int kboff = (nq >> 3) * 272 + (nq & 7) * 2;
            #pragma unroll
            for (int mt = 0; mt < 2; ++mt) {
                float zq[4], sq[4];
                #pragma unroll
                for (int e = 0; e < 4; ++e) {
                    const float be  = (e == 0) ? b04.x : (e == 1) ? b04.y : (e == 2) ? b04.z : b04.w;
                    const float w0e = (e == 0) ? wr0.x : (e == 1) ? wr0.y : (e == 2) ? wr0.z : wr0.w;
                    const float w1e = (e == 0) ? wr1.x : (e == 1) ? wr1.y : (e == 2) ? wr1.z : wr1.w;
                    const float pre = zacc[mt][nt][e] + be + tv * w0e + xv[mt] * w1e;
                    const float z = fast_tanh(pre);
                    zq[e] = z;
                    sq[e] = (1.f - z * z) * w1e;
                }
                const int off = mt * 17408 + kboff + l15 * 16;
                *(uint2*)(smem + off)         = make_uint2(cvt_pk_bf16(zq[0], zq[1]), cvt_pk_bf16(zq[2], zq[3]));
                *(uint2*)(smem + 34816 + off) = make_uint2(cvt_pk_bf16(sq[0], sq[1]), cvt_pk_bf16(sq[2], sq[3]));
            }
        }
    }
    __syncthreads();

    // ---- phase 2: layer-1 GEMM (bf16 MFMA), fully unrolled, peeled tail ----
    f32x4 accp[2][4] = {};
    f32x4 acct[2][4] = {};

    const int aoff0 = l15 * 16 + l16 * 272;
    const char* __restrict__ Wb = (const char*)W1q + (((size_t)(w * 4) * 16) << 10) + lane * 16;

    bf16x8 za0[2], ta0[2], bf0[4];
    #pragma unroll
    for (int mt = 0; mt < 2; ++mt) {
        za0[mt] = *(const bf16x8*)(smem + mt * 17408 + aoff0);
        ta0[mt] = *(const bf16x8*)(smem + 34816 + mt * 17408 + aoff0);
    }
    #pragma unroll
    for (int nt = 0; nt < 4; ++nt)
        bf0[nt] = *(const bf16x8*)(Wb + nt * 16384);

    #pragma unroll
    for (int ks = 0; ks < 15; ++ks) {
        bf16x8 za1[2], ta1[2], bf1[4];
        const int aoff = aoff0 + (ks + 1) * 1088;
        #pragma unroll
        for (int mt = 0; mt < 2; ++mt) {
            za1[mt] = *(const bf16x8*)(smem + mt * 17408 + aoff);
            ta1[mt] = *(const bf16x8*)(smem + 34816 + mt * 17408 + aoff);
        }
        #pragma unroll
        for (int nt = 0; nt < 4; ++nt)
            bf1[nt] = *(const bf16x8*)(Wb + nt * 16384 + (ks + 1) * 1024);
        #pragma unroll
        for (int mt = 0; mt < 2; ++mt)
            #pragma unroll
            for (int nt = 0; nt < 4; ++nt) {
                accp[mt][nt] = __builtin_amdgcn_mfma_f32_16x16x32_bf16(za0[mt], bf0[nt], accp[mt][nt], 0, 0, 0);
                acct[mt][nt] = __builtin_amdgcn_mfma_f32_16x16x32_bf16(ta0[mt], bf0[nt], acct[mt][nt], 0, 0, 0);
            }
        #pragma unroll
        for (int mt = 0; mt < 2; ++mt) { za0[mt] = za1[mt]; ta0[mt] = ta1[mt]; }
        #pragma unroll
        for (int nt = 0; nt < 4; ++nt) bf0[nt] = bf1[nt];
    }
    #pragma unroll
    for (int mt = 0; mt < 2; ++mt)
        #pragma unroll
        for (int nt = 0; nt < 4; ++nt) {
            accp[mt][nt] = __builtin_amdgcn_mfma_f32_16x16x32_bf16(za0[mt], bf0[nt], accp[mt][nt], 0, 0, 0);
            acct[mt][nt] = __builtin_amdgcn_mfma_f32_16x16x32_bf16(ta0[mt], bf0[nt], acct[mt][nt], 0, 0, 0);
        }

    // ---- phase 3: tanh/JVP epilogue + 512->1 dot ----
    float py[2][4] = {}, pj[2][4] = {};
    #pragma unroll
    for (int nt = 0; nt < 4; ++nt) {
        const int n = w * 64 + nt * 16 + l15;
        const float b1v = b1[n];
        const float w2v = W2[n];
        #pragma unroll
        for (int mt = 0; mt < 2; ++mt)
            #pragma unroll
            for (int e = 0; e < 4; ++e) {
                const float z2  = fast_tanh(accp[mt][nt][e] + b1v);
                const float dz2 = (1.f - z2 * z2) * acct[mt][nt][e];
                py[mt][e] += z2  * w2v;
                pj[mt][e] += dz2 * w2v;
            }
    }
    #pragma unroll
    for (int off = 1; off < 16; off <<= 1)
        #pragma unroll
        for (int mt = 0; mt < 2; ++mt)
            #pragma unroll
            for (int e = 0; e < 4; ++e) {
                py[mt][e] += __shfl_xor(py[mt][e], off);
                pj[mt][e] += __shfl_xor(pj[mt][e], off);
            }

    __syncthreads();
    float* part = (float*)smem;         // [8 w][2 mt][16 row][2]
    if (l15 == 0) {
        const int q = l16;
        #pragma unroll
        for (int mt = 0; mt < 2; ++mt)
            #pragma unroll
            for (int e = 0; e < 4; ++e) {
                const int idx = ((w * 2 + mt) * 16 + 4 * q + e) * 2;
                part[idx]     = py[mt][e];
                part[idx + 1] = pj[mt][e];
            }
    }
    __syncthreads();
    if (tid < 64) {
        const int mt = tid >> 5, row = (tid >> 1) & 15, wh = tid & 1;
        float s = 0.f;
        #pragma unroll
        for (int w8 = 0; w8 < 8; ++w8)
            s += part[((w8 * 2 + mt) * 16 + row) * 2 + wh];
        const int grow = row0 + mt * 16 + row;
        if (wh == 0) out[grow] = s + b2[0];
        else         out[131072 + grow] = s;
    }
}

// ---------------------------------------------------------------------------
extern "C" void kernel_launch(void* const* d_in, const int* in_sizes, int n_in,
                              void* d_out, int out_size, void* d_ws, size_t ws_size,
                              hipStream_t stream)
{
    (void)in_sizes; (void)n_in; (void)out_size; (void)ws_size;

    const float* t     = (const float*)d_in[0];
    const float* x     = (const float*)d_in[1];
    const float* m1_W0 = (const float*)d_in[2];
    const float* m1_b0 = (const float*)d_in[3];
    const float* m1_W1 = (const float*)d_in[4];
    const float* m1_b1 = (const float*)d_in[5];
    const float* m1_W2 = (const float*)d_in[6];
    const float* m1_b2 = (const float*)d_in[7];
    const float* m2_W0 = (const float*)d_in[8];
    const float* m2_b0 = (const float*)d_in[9];
    const float* m2_W1 = (const float*)d_in[10];
    const float* m2_b1 = (const float*)d_in[11];
    const float* m2_W2 = (const float*)d_in[12];
    const float* m2_b2 = (const float*)d_in[13];
    const float* d_W0  = (const float*)d_in[14];
    const float* d_b0  = (const float*)d_in[15];
    const float* d_W1  = (const float*)d_in[16];
    const float* d_b1  = (const float*)d_in[17];
    const float* d_W2  = (const float*)d_in[18];
    const float* d_b2  = (const float*)d_in[19];

    // ws layout (peak 0x2290000 = 36.25 MB):
    // [0x0000000] W1q 512K ; [0x0080000] W0q 64K
    // [0x0090000] Hc 16M (overlays W1tq 1M @0x90000 + A1q 2M @0x190000,
    //                     both dead before gemm3 writes Hc)
    // [0x1090000] A2q 2M ; [0x1290000] W2q 16M
    char* base = (char*)d_ws;
    unsigned short* W1q  = (unsigned short*)(base);
    unsigned short* W0q  = (unsigned short*)(base + 0x80000);
    unsigned short* Hc   = (unsigned short*)(base + 0x90000);
    unsigned short* W1tq = (unsigned short*)(base + 0x90000);    // overlay
    unsigned short* A1q  = (unsigned short*)(base + 0x190000);   // overlay
    unsigned short* A2q  = (unsigned short*)(base + 0x1090000);
    unsigned short* W2q  = (unsigned short*)(base + 0x1290000);

    // one launch: all independent prework in parallel
    prework_k<<<dim3(9344), dim3(256), 0, stream>>>(d_W1, d_W0, m1_W1, m2_W1,
                                                    m1_W2, m2_W2, x,
                                                    m1_W0, m2_W0, m1_b0, m2_b0,
                                                    W1q, W0q, W1tq, W2q, A1q);

    gemm2_k<<<dim3(16, 16), dim3(512), 0, stream>>>(A1q, W1tq, m1_b1, m2_b1, A2q);
    gemm3_k<<<dim3(64, 8), dim3(512), 0, stream>>>(A2q, W2q, m1_b2, m2_b2, Hc);

    dimwise_k<<<dim3(4096), dim3(512), 0, stream>>>(Hc, x, t, W1q, W0q,
                                                    d_W0, d_b0, d_b1, d_W2, d_b2,
                                                    (float*)d_out);
}